// Round 4
// baseline (781.593 us; speedup 1.0000x reference)
//
#include <hip/hip_runtime.h>

// Problem constants (from reference)
constexpr int N   = 50000;
constexpr int E   = 800000;
constexpr int FIN = 512;
constexpr int H1v = 256;
constexpr int H2v = 32;
constexpr int Cv  = 16;

constexpr int NBLK = (N + 1023) / 1024;  // 49 scan blocks

typedef __attribute__((ext_vector_type(8))) short short8;            // 8 bf16 (MFMA frag)
typedef __attribute__((ext_vector_type(4))) float f32x4;             // MFMA C/D frag
typedef __attribute__((ext_vector_type(4))) unsigned short us4;      // 4 bf16
typedef __attribute__((ext_vector_type(4))) unsigned int uint4v;

// fp32 -> bf16 round-to-nearest-even, and back
__device__ inline unsigned short f2bf(float f) {
    unsigned u = __float_as_uint(f);
    return (unsigned short)((u + 0x7FFFu + ((u >> 16) & 1u)) >> 16);
}
__device__ inline float bf2f(unsigned short b) { return __uint_as_float(((unsigned)b) << 16); }

// ---------------- init: cnt zeroing + W1 split, fused (independent data) --------
// Blocks 0..63: W1 split into bf16 hi/lo MFMA B-frag layout.
// Blocks 64.. : cnt[0..N] = 0.
// W-frag layout: tile (ktg 0..15, ntg 0..15): B[k][n], k=ktg*32+(l>>4)*8+j,
// n=ntg*16+(l&15); tile base = ((ktg*16+ntg)*2)*512; hi at +l*8, lo at +512+l*8.

__global__ __launch_bounds__(256) void k_init(const float* __restrict__ W,
                                              unsigned short* __restrict__ Wf,
                                              int* __restrict__ cnt) {
    const int b = blockIdx.x;
    if (b < 64) {
        int t = b * 256 + threadIdx.x;  // 0..16383
        int l = t & 63, nt = (t >> 6) & 15, kt = t >> 10;
        int n = nt * 16 + (l & 15);
        int kb = kt * 32 + (l >> 4) * 8;
        short8 h8, l8;
#pragma unroll
        for (int j = 0; j < 8; ++j) {
            float w = W[(size_t)(kb + j) * H1v + n];
            unsigned short h = f2bf(w);
            h8[j] = (short)h;
            l8[j] = (short)f2bf(w - bf2f(h));
        }
        size_t base = ((size_t)(kt * 16 + nt) * 2) * 512 + (size_t)l * 8;
        *(short8*)(Wf + base) = h8;
        *(short8*)(Wf + base + 512) = l8;
    } else {
        int i = (b - 64) * 256 + threadIdx.x;
        if (i <= N) cnt[i] = 0;
    }
}

// ---------------- degree histogram / CSR build ----------------

__global__ __launch_bounds__(256) void k_hist(const int* __restrict__ dst,
                                              int* __restrict__ cnt) {
    int e = blockIdx.x * 256 + threadIdx.x;
    if (e < E) atomicAdd(&cnt[dst[e]], 1);
}

// Phase 1: per-block (1024 elems) sums.
__global__ __launch_bounds__(256) void k_scan_part(const int* __restrict__ cnt,
                                                   int* __restrict__ bsum) {
    __shared__ int red[256];
    const int t = threadIdx.x;
    const int base = blockIdx.x * 1024 + t * 4;
    int s = 0;
#pragma unroll
    for (int i = 0; i < 4; ++i) {
        int idx = base + i;
        if (idx < N) s += cnt[idx];
    }
    red[t] = s;
    __syncthreads();
    for (int off = 128; off > 0; off >>= 1) {
        if (t < off) red[t] += red[t + off];
        __syncthreads();
    }
    if (t == 0) bsum[blockIdx.x] = red[0];
}

// Phase 2 (fused top + final): block offset computed in-block from bsum (49 ints,
// one wave), then block-local scan -> row_ptr, cursor, dinv. In-place safe vs cnt:
// each block reads only its own disjoint 1024-range into registers before writes.
__global__ __launch_bounds__(256) void k_scan_final(const int* __restrict__ cnt,
                                                    const int* __restrict__ bsum,
                                                    int* __restrict__ row_ptr,
                                                    int* __restrict__ cursor,
                                                    float* __restrict__ dinv) {
    __shared__ int sums[256];
    __shared__ int s_bofs, s_tot;
    const int t = threadIdx.x;

    if (t < 64) {  // one wave: prefix-of-my-block + grand total over bsum[49]
        int v = (t < NBLK) ? bsum[t] : 0;
        int pre = (t < (int)blockIdx.x) ? v : 0;
#pragma unroll
        for (int off = 32; off > 0; off >>= 1) {
            pre += __shfl_down(pre, off, 64);
            v   += __shfl_down(v, off, 64);
        }
        if (t == 0) { s_bofs = pre; s_tot = v; }
    }

    const int base = blockIdx.x * 1024 + t * 4;
    int v[4];
    int local = 0;
#pragma unroll
    for (int i = 0; i < 4; ++i) {
        int idx = base + i;
        v[i] = (idx < N) ? cnt[idx] : 0;
        local += v[i];
    }
    sums[t] = local;
    __syncthreads();
    for (int off = 1; off < 256; off <<= 1) {
        int u = (t >= off) ? sums[t - off] : 0;
        __syncthreads();
        sums[t] += u;
        __syncthreads();
    }
    int run = s_bofs + sums[t] - local;  // exclusive thread offset
#pragma unroll
    for (int i = 0; i < 4; ++i) {
        int idx = base + i;
        if (idx < N) {
            row_ptr[idx] = run;
            cursor[idx] = run;
            dinv[idx] = rsqrtf(1.0f + (float)v[i]);  // +1 self-loop
        }
        run += v[i];
    }
    if (blockIdx.x == NBLK - 1 && t == 0) row_ptr[N] = s_tot;  // == E
}

__global__ __launch_bounds__(256) void k_permute(const int* __restrict__ src,
                                                 const int* __restrict__ dst,
                                                 int* __restrict__ cursor,
                                                 int* __restrict__ srcs) {
    int e = blockIdx.x * 256 + threadIdx.x;
    if (e < E) {
        int pos = atomicAdd(&cursor[dst[e]], 1);
        srcs[pos] = src[e];
    }
}

// ---------------- GEMM 1 (MFMA, split-bf16 x3): [N,512]@[512,256] ---------------
// ROUND 12: round-11's issue-reorder was a NULL (identical counters) -> the
// stall is not the vmcnt drain order; it's that at 2.6 waves/SIMD every latency
// (B L2 ~300cy, staging HBM ~900cy, barrier drain) lands on an empty SIMD.
// KEY FACT: VGPR_Count is exactly 64 = the 8-waves/SIMD occupancy boundary
// (gfx950 steps at 64/128/256), but __launch_bounds__(256,4) has been CAPPING
// residency at 4 waves/SIMD. Fix: lb(256,8). LDS 16KB x 8 = 128KB <= 160KB.
// Grid supplies 6.1 blocks/CU -> expect ~24 waves/CU (~70%). No structural
// change; isolates the occupancy cap as the variable. If VGPR spills appear
// (scratch/WRITE_SIZE jump), revert to (256,4).
// (R8: no deeper reg pipeline. R9: LDS staging fine. R10: occupancy lever real.)

__device__ inline void split_pair(float x0, float x1, unsigned& hp, unsigned& lp) {
    unsigned u0 = __float_as_uint(x0), u1 = __float_as_uint(x1);
    unsigned h0 = u0 & 0xffff0000u, h1 = u1 & 0xffff0000u;
    float l0 = x0 - __uint_as_float(h0);
    float l1 = x1 - __uint_as_float(h1);
    hp = __builtin_amdgcn_perm(u1, u0, 0x07060302u);  // [u0.hi16, u1.hi16]
    lp = __builtin_amdgcn_perm(__float_as_uint(l1), __float_as_uint(l0), 0x07060302u);
}

__device__ inline void split_frag(const float4& a, const float4& b, short8& hi, short8& lo) {
    unsigned h0, h1, h2, h3, l0, l1, l2, l3;
    split_pair(a.x, a.y, h0, l0);
    split_pair(a.z, a.w, h1, l1);
    split_pair(b.x, b.y, h2, l2);
    split_pair(b.z, b.w, h3, l3);
    uint4v h, l;
    h[0] = h0; h[1] = h1; h[2] = h2; h[3] = h3;
    l[0] = l0; l[1] = l1; l[2] = l2; l[3] = l3;
    hi = __builtin_bit_cast(short8, h);
    lo = __builtin_bit_cast(short8, l);
}

// Stage one 64-row x 32-col fp32 X tile into LDS (8 KB), XOR-swizzled.
// Chunk q in [0,512): row = q>>3, slot = q&7; LDS byte = q*16 (linear, as
// global_load_lds requires); source granule = slot ^ (row&7) (involution).
// Rows past N are redirected to row 0 (their acc is never stored).
__device__ inline void stage_x_tile(const float* __restrict__ X, int brow, int k0,
                                    float* lds, int tid) {
    const int wbase = tid & ~63;  // wave-uniform chunk base
#pragma unroll
    for (int c = 0; c < 2; ++c) {
        int q = c * 256 + tid;
        int row = q >> 3;
        int gc = ((q & 7) ^ (row & 7)) << 2;  // swizzled source col (floats)
        int r = brow + row;
        const float* src = X + (size_t)(r < N ? r : 0) * FIN + k0 + gc;
        float* dst = lds + (size_t)(c * 256 + wbase) * 4;  // wave-uniform, lane adds 16B
        __builtin_amdgcn_global_load_lds((const __attribute__((address_space(1))) void*)src,
                                         (__attribute__((address_space(3))) void*)dst,
                                         16, 0, 0);
    }
}

__global__ __launch_bounds__(256, 8) void k_gemm1_mfma(const float* __restrict__ X,
                                                       const unsigned short* __restrict__ Wf,
                                                       const float* __restrict__ dinv,
                                                       unsigned short* __restrict__ Hout) {
    __shared__ float As[2][2048];  // 2 x (64 rows x 32 cols) fp32 = 16 KB
    const int tid = threadIdx.x;
    const int w = tid >> 6, l = tid & 63;
    const int wr = w >> 1, wc = w & 1;        // wave: 32-row group x 64-col group
    const int brow = blockIdx.x * 64;         // block row base
    const int row0 = brow + wr * 32;          // this wave's global row base
    const int wrow = wr * 32;                 // this wave's LDS-local row base
    const int colb = blockIdx.y;
    const int lm = l & 15;
    const int lk2 = (l >> 4) * 2;             // fragment granule pair base (16B units)

    // B frag lane pointer (tiles ntg = colb*8 + wc*4 + j)
    const unsigned short* bp0 = Wf + (size_t)(colb * 8 + wc * 4) * 1024 + (size_t)l * 8;

    f32x4 acc[2][4];
#pragma unroll
    for (int i = 0; i < 2; ++i)
#pragma unroll
        for (int j = 0; j < 4; ++j) acc[i][j] = (f32x4)0.f;

    // prologue: stage K-tile 0
    stage_x_tile(X, brow, 0, As[0], tid);

    for (int ktg = 0; ktg < 16; ++ktg) {
        const int cur = ktg & 1;
        __syncthreads();  // drains vmcnt(0): As[cur] staged & visible

        // B frags (L2-hot, already frag layout, lane-contiguous)
        const unsigned short* bp = bp0 + (size_t)ktg * 16384;  // ktg*16 tiles * 1024
        short8 Bh[4], Bl[4];
#pragma unroll
        for (int j = 0; j < 4; ++j) {
            Bh[j] = *(const short8*)(bp + j * 1024);
            Bl[j] = *(const short8*)(bp + j * 1024 + 512);
        }

        // stage next K-tile (completes during MFMA phase, drained at barrier)
        if (ktg < 15) stage_x_tile(X, brow, (ktg + 1) * 32, As[cur ^ 1], tid);

        // A frags from LDS (swizzled ds_read_b128), then fp32 -> bf16 hi/lo split
        short8 Ah[2], Al[2];
        const float* Ab = As[cur];
#pragma unroll
        for (int i = 0; i < 2; ++i) {
            int row = wrow + i * 16 + lm;
            const float* rbp = Ab + row * 32;
            int p = row & 7;
            float4 a0 = *(const float4*)(rbp + ((lk2 ^ p) << 2));
            float4 a1 = *(const float4*)(rbp + (((lk2 + 1) ^ p) << 2));
            split_frag(a0, a1, Ah[i], Al[i]);
        }

        // MFMA: 2x4 16x16 tiles, 3 split terms (AhBh + AhBl + AlBh)
#pragma unroll
        for (int i = 0; i < 2; ++i)
#pragma unroll
            for (int j = 0; j < 4; ++j) {
                acc[i][j] = __builtin_amdgcn_mfma_f32_16x16x32_bf16(Ah[i], Bh[j], acc[i][j], 0, 0, 0);
                acc[i][j] = __builtin_amdgcn_mfma_f32_16x16x32_bf16(Ah[i], Bl[j], acc[i][j], 0, 0, 0);
                acc[i][j] = __builtin_amdgcn_mfma_f32_16x16x32_bf16(Al[i], Bh[j], acc[i][j], 0, 0, 0);
            }
    }

    // ---- epilogue: C row = (l>>4)*4 + reg, col = l&15 ; *dinv[row], store bf16 ----
    const int col0 = colb * 128 + wc * 64;
#pragma unroll
    for (int i = 0; i < 2; ++i) {
        int rbase = row0 + i * 16 + (l >> 4) * 4;
        float dv[4];
        bool okr[4];
#pragma unroll
        for (int r = 0; r < 4; ++r) {
            int rr = rbase + r;
            okr[r] = rr < N;
            dv[r] = okr[r] ? dinv[rr] : 0.f;
        }
#pragma unroll
        for (int j = 0; j < 4; ++j) {
            int col = col0 + j * 16 + lm;
#pragma unroll
            for (int r = 0; r < 4; ++r)
                if (okr[r]) Hout[(size_t)(rbase + r) * H1v + col] = f2bf(acc[i][j][r] * dv[r]);
        }
    }
}

// ---------------- GEMM 2: [N,256] @ [256,32] fp32 in, *dinv, bf16 out ----------------

__global__ __launch_bounds__(256) void k_gemm2(const float* __restrict__ A,
                                               const float* __restrict__ W,
                                               const float* __restrict__ dinv,
                                               unsigned short* __restrict__ Hout) {
    __shared__ float Ws[H1v * H2v];  // 32 KB
    const int tid = threadIdx.x;
#pragma unroll
    for (int i = 0; i < 8; ++i) {
        int off = tid * 4 + i * 1024;
        *(float4*)(&Ws[off]) = *(const float4*)(W + off);
    }
    __syncthreads();

    const int row = blockIdx.x * 8 + (tid >> 5);
    const int col = tid & 31;
    if (row >= N) return;
    const float* arow = A + (size_t)row * H1v;
    float sum = 0.f;
#pragma unroll 4
    for (int k = 0; k < H1v; k += 4) {
        float4 a4 = *(const float4*)(arow + k);
        sum = fmaf(a4.x, Ws[(k + 0) * H2v + col], sum);
        sum = fmaf(a4.y, Ws[(k + 1) * H2v + col], sum);
        sum = fmaf(a4.z, Ws[(k + 2) * H2v + col], sum);
        sum = fmaf(a4.w, Ws[(k + 3) * H2v + col], sum);
    }
    Hout[(size_t)row * H2v + col] = f2bf(sum * dinv[row]);
}

// ---------------- CSR aggregation (atomic-free, bf16 messages, fp32 accum) -------
// h holds bf16 h'[i] = dinv[i]*(a@W)[i].  out[d] = dinv[d]*(sum h'[s] + h'[d]) + b

__global__ __launch_bounds__(256) void k_agg_d256(const unsigned short* __restrict__ h,
                                                  const int* __restrict__ rp,
                                                  const int* __restrict__ srcs,
                                                  const float* __restrict__ dinv,
                                                  const float* __restrict__ bias,
                                                  float* __restrict__ out) {
    const int wave = threadIdx.x >> 6;
    const int lane = threadIdx.x & 63;
    const int d = blockIdx.x * 4 + wave;
    if (d >= N) return;
    const int beg = rp[d], end = rp[d + 1];
    const int fo = lane * 4;
    us4 sv = *(const us4*)(h + (size_t)d * H1v + fo);  // self-loop
    float ax = bf2f(sv.x), ay = bf2f(sv.y), az = bf2f(sv.z), aw = bf2f(sv.w);
    int j = beg;
    for (; j + 3 < end; j += 4) {  // 4 independent gathers in flight
        int s0 = srcs[j], s1 = srcs[j + 1], s2 = srcs[j + 2], s3 = srcs[j + 3];
        us4 v0 = *(const us4*)(h + (size_t)s0 * H1v + fo);
        us4 v1 = *(const us4*)(h + (size_t)s1 * H1v + fo);
        us4 v2 = *(const us4*)(h + (size_t)s2 * H1v + fo);
        us4 v3 = *(const us4*)(h + (size_t)s3 * H1v + fo);
        ax += bf2f(v0.x) + bf2f(v1.x) + bf2f(v2.x) + bf2f(v3.x);
        ay += bf2f(v0.y) + bf2f(v1.y) + bf2f(v2.y) + bf2f(v3.y);
        az += bf2f(v0.z) + bf2f(v1.z) + bf2f(v2.z) + bf2f(v3.z);
        aw += bf2f(v0.w) + bf2f(v1.w) + bf2f(v2.w) + bf2f(v3.w);
    }
    for (; j < end; ++j) {
        us4 v = *(const us4*)(h + (size_t)srcs[j] * H1v + fo);
        ax += bf2f(v.x); ay += bf2f(v.y); az += bf2f(v.z); aw += bf2f(v.w);
    }
    const float di = dinv[d];
    const float4 b4 = *(const float4*)(bias + fo);
    float4 o;
    o.x = fmaxf(fmaf(di, ax, b4.x), 0.f);
    o.y = fmaxf(fmaf(di, ay, b4.y), 0.f);
    o.z = fmaxf(fmaf(di, az, b4.z), 0.f);
    o.w = fmaxf(fmaf(di, aw, b4.w), 0.f);
    *(float4*)(out + (size_t)d * H1v + fo) = o;
}

// ---------------- fused: agg over h2 (D=32) + GEMM3 [32x16] -> h3 bf16 ----------
// Block = 8 dst rows. Phase 1: thread (sub,f) aggregates row sub, dim f; a2 row
// (relu(dinv*sum+b2)) goes to LDS (padded stride 33). Phase 2: threads 0..127
// compute 8x16 GEMM3 outputs from LDS, *dinv, store bf16. Kills the a2 buffer.

__global__ __launch_bounds__(256) void k_agg32_gemm3(const unsigned short* __restrict__ h2,
                                                     const int* __restrict__ rp,
                                                     const int* __restrict__ srcs,
                                                     const float* __restrict__ dinv,
                                                     const float* __restrict__ b2,
                                                     const float* __restrict__ W3,
                                                     unsigned short* __restrict__ h3) {
    __shared__ float als[8][33];       // +1 pad: kills 4-way stride-32 conflicts
    __shared__ float W3s[H2v * Cv];    // 512 floats
    const int t = threadIdx.x;
    *(float2*)(&W3s[t * 2]) = *(const float2*)(W3 + t * 2);

    const int sub = t >> 5, f = t & 31;
    const int d = blockIdx.x * 8 + sub;  // N % 8 == 0
    const int beg = rp[d], end = rp[d + 1];
    float acc = bf2f(h2[(size_t)d * H2v + f]);  // self-loop
    int j = beg;
    for (; j + 3 < end; j += 4) {
        float v0 = bf2f(h2[(size_t)srcs[j] * H2v + f]);
        float v1 = bf2f(h2[(size_t)srcs[j + 1] * H2v + f]);
        float v2 = bf2f(h2[(size_t)srcs[j + 2] * H2v + f]);
        float v3 = bf2f(h2[(size_t)srcs[j + 3] * H2v + f]);
        acc += v0 + v1 + v2 + v3;
    }
    for (; j < end; ++j) acc += bf2f(h2[(size_t)srcs[j] * H2v + f]);
    als[sub][f] = fmaxf(fmaf(dinv[d], acc, b2[f]), 0.f);
    __syncthreads();

    if (t < 128) {
        const int row = t >> 4, col = t & 15;
        float sum = 0.f;
#pragma unroll
        for (int k = 0; k < H2v; ++k) sum = fmaf(als[row][k], W3s[k * Cv + col], sum);
        const int gr = blockIdx.x * 8 + row;
        h3[(size_t)gr * Cv + col] = f2bf(sum * dinv[gr]);
    }
}

// ---------------- final aggregation over h3 (D=16) -> out fp32 ----------------

__global__ __launch_bounds__(256) void k_agg16(const unsigned short* __restrict__ h,
                                               const int* __restrict__ rp,
                                               const int* __restrict__ srcs,
                                               const float* __restrict__ dinv,
                                               const float* __restrict__ bias,
                                               float* __restrict__ out) {
    const int sub = threadIdx.x >> 4;
    const int f = threadIdx.x & 15;
    const int d = blockIdx.x * 16 + sub;
    if (d >= N) return;
    const int beg = rp[d], end = rp[d + 1];
    float acc = bf2f(h[(size_t)d * Cv + f]);  // self-loop
    int j = beg;
    for (; j + 3 < end; j += 4) {
        float v0 = bf2f(h[(size_t)srcs[j] * Cv + f]);
        float v1 = bf2f(h[(size_t)srcs[j + 1] * Cv + f]);
        float v2 = bf2f(h[(size_t)srcs[j + 2] * Cv + f]);
        float v3 = bf2f(h[(size_t)srcs[j + 3] * Cv + f]);
        acc += v0 + v1 + v2 + v3;
    }
    for (; j < end; ++j) acc += bf2f(h[(size_t)srcs[j] * Cv + f]);
    out[(size_t)d * Cv + f] = fmaf(dinv[d], acc, bias[f]);
}

// ---------------- launch ----------------

extern "C" void kernel_launch(void* const* d_in, const int* in_sizes, int n_in,
                              void* d_out, int out_size, void* d_ws, size_t ws_size,
                              hipStream_t stream) {
    const float* x  = (const float*)d_in[0];
    const int*   ei = (const int*)d_in[1];
    const float* W1 = (const float*)d_in[2];
    const float* b1 = (const float*)d_in[3];
    const float* W2 = (const float*)d_in[4];
    const float* b2 = (const float*)d_in[5];
    const float* W3 = (const float*)d_in[6];
    const float* b3 = (const float*)d_in[7];
    const int* src = ei;       // edge_index[0]
    const int* dst = ei + E;   // edge_index[1]
    float* out = (float*)d_out;

    // Workspace layout (bytes):
    // [0       ] dinv    float[50000]
    // [0x40000 ] cnt/rp  int[50001]   (in-place scan)
    // [0x80000 ] cursor  int[50000]
    // [0xB2000 ] bsum    int[49]
    // [0xC0000 ] srcs    int[800000]
    // [4 MiB   ] Wsplit  ushort[262144]  (512 KB)
    // [5 MiB   ] h1 bf16, a1 fp32, h2 bf16, h3 bf16   (a2 eliminated)
    char* ws = (char*)d_ws;
    float* dinv   = (float*)ws;
    int*   cnt    = (int*)(ws + 0x40000);
    int*   rp     = cnt;
    int*   cursor = (int*)(ws + 0x80000);
    int*   bsum   = (int*)(ws + 0xB2000);
    int*   srcs   = (int*)(ws + 0xC0000);
    unsigned short* wsplit = (unsigned short*)(ws + (size_t)4 * 1024 * 1024);
    char* p = ws + (size_t)5 * 1024 * 1024;
    unsigned short* h1 = (unsigned short*)p; p += (size_t)N * H1v * sizeof(unsigned short);
    float*          a1 = (float*)p;          p += (size_t)N * H1v * sizeof(float);
    unsigned short* h2 = (unsigned short*)p; p += (size_t)N * H2v * sizeof(unsigned short);
    unsigned short* h3 = (unsigned short*)p;

    // CSR build + weight split: 5 dispatches
    k_init<<<64 + (N + 256) / 256, 256, 0, stream>>>(W1, wsplit, cnt);
    k_hist<<<(E + 255) / 256, 256, 0, stream>>>(dst, cnt);
    k_scan_part<<<NBLK, 256, 0, stream>>>(cnt, bsum);
    k_scan_final<<<NBLK, 256, 0, stream>>>(cnt, bsum, rp, cursor, dinv);
    k_permute<<<(E + 255) / 256, 256, 0, stream>>>(src, dst, cursor, srcs);

    // ---- layer 1: 512 -> 256 (MFMA, LDS-staged double-buffer, 64x128 tiles), ReLU ----
    dim3 g1((N + 63) / 64, 2);
    k_gemm1_mfma<<<g1, 256, 0, stream>>>(x, wsplit, dinv, h1);
    k_agg_d256<<<(N + 3) / 4, 256, 0, stream>>>(h1, rp, srcs, dinv, b1, a1);

    // ---- layer 2: 256 -> 32, ReLU ----
    k_gemm2<<<N / 8, 256, 0, stream>>>(a1, W2, dinv, h2);

    // ---- fused: agg(h2) + GEMM3 -> h3 ----
    k_agg32_gemm3<<<N / 8, 256, 0, stream>>>(h2, rp, srcs, dinv, b2, W3, h3);

    // ---- final aggregation -> out ----
    k_agg16<<<(N + 15) / 16, 256, 0, stream>>>(h3, rp, srcs, dinv, b3, out);
}

// Round 5
// 449.006 us; speedup vs baseline: 1.7407x; 1.7407x over previous
//
#include <hip/hip_runtime.h>

// Problem constants (from reference)
constexpr int N   = 50000;
constexpr int E   = 800000;
constexpr int FIN = 512;
constexpr int H1v = 256;
constexpr int H2v = 32;
constexpr int Cv  = 16;

constexpr int NBLK = (N + 1023) / 1024;  // 49 scan blocks

typedef __attribute__((ext_vector_type(8))) short short8;            // 8 bf16 (MFMA frag)
typedef __attribute__((ext_vector_type(4))) float f32x4;             // MFMA C/D frag
typedef __attribute__((ext_vector_type(4))) unsigned short us4;      // 4 bf16
typedef __attribute__((ext_vector_type(4))) unsigned int uint4v;

// fp32 -> bf16 round-to-nearest-even, and back
__device__ inline unsigned short f2bf(float f) {
    unsigned u = __float_as_uint(f);
    return (unsigned short)((u + 0x7FFFu + ((u >> 16) & 1u)) >> 16);
}
__device__ inline float bf2f(unsigned short b) { return __uint_as_float(((unsigned)b) << 16); }

// ---------------- init: cnt zeroing + W1 split, fused (independent data) --------
// Blocks 0..63: W1 split into bf16 hi/lo MFMA B-frag layout.
// Blocks 64.. : cnt[0..N] = 0.
// W-frag layout: tile (ktg 0..15, ntg 0..15): B[k][n], k=ktg*32+(l>>4)*8+j,
// n=ntg*16+(l&15); tile base = ((ktg*16+ntg)*2)*512; hi at +l*8, lo at +512+l*8.

__global__ __launch_bounds__(256) void k_init(const float* __restrict__ W,
                                              unsigned short* __restrict__ Wf,
                                              int* __restrict__ cnt) {
    const int b = blockIdx.x;
    if (b < 64) {
        int t = b * 256 + threadIdx.x;  // 0..16383
        int l = t & 63, nt = (t >> 6) & 15, kt = t >> 10;
        int n = nt * 16 + (l & 15);
        int kb = kt * 32 + (l >> 4) * 8;
        short8 h8, l8;
#pragma unroll
        for (int j = 0; j < 8; ++j) {
            float w = W[(size_t)(kb + j) * H1v + n];
            unsigned short h = f2bf(w);
            h8[j] = (short)h;
            l8[j] = (short)f2bf(w - bf2f(h));
        }
        size_t base = ((size_t)(kt * 16 + nt) * 2) * 512 + (size_t)l * 8;
        *(short8*)(Wf + base) = h8;
        *(short8*)(Wf + base + 512) = l8;
    } else {
        int i = (b - 64) * 256 + threadIdx.x;
        if (i <= N) cnt[i] = 0;
    }
}

// ---------------- degree histogram / CSR build ----------------

__global__ __launch_bounds__(256) void k_hist(const int* __restrict__ dst,
                                              int* __restrict__ cnt) {
    int e = blockIdx.x * 256 + threadIdx.x;
    if (e < E) atomicAdd(&cnt[dst[e]], 1);
}

// Phase 1: per-block (1024 elems) sums.
__global__ __launch_bounds__(256) void k_scan_part(const int* __restrict__ cnt,
                                                   int* __restrict__ bsum) {
    __shared__ int red[256];
    const int t = threadIdx.x;
    const int base = blockIdx.x * 1024 + t * 4;
    int s = 0;
#pragma unroll
    for (int i = 0; i < 4; ++i) {
        int idx = base + i;
        if (idx < N) s += cnt[idx];
    }
    red[t] = s;
    __syncthreads();
    for (int off = 128; off > 0; off >>= 1) {
        if (t < off) red[t] += red[t + off];
        __syncthreads();
    }
    if (t == 0) bsum[blockIdx.x] = red[0];
}

// Phase 2 (fused top + final): block offset computed in-block from bsum (49 ints,
// one wave), then block-local scan -> row_ptr, cursor, dinv. In-place safe vs cnt:
// each block reads only its own disjoint 1024-range into registers before writes.
__global__ __launch_bounds__(256) void k_scan_final(const int* __restrict__ cnt,
                                                    const int* __restrict__ bsum,
                                                    int* __restrict__ row_ptr,
                                                    int* __restrict__ cursor,
                                                    float* __restrict__ dinv) {
    __shared__ int sums[256];
    __shared__ int s_bofs, s_tot;
    const int t = threadIdx.x;

    if (t < 64) {  // one wave: prefix-of-my-block + grand total over bsum[49]
        int v = (t < NBLK) ? bsum[t] : 0;
        int pre = (t < (int)blockIdx.x) ? v : 0;
#pragma unroll
        for (int off = 32; off > 0; off >>= 1) {
            pre += __shfl_down(pre, off, 64);
            v   += __shfl_down(v, off, 64);
        }
        if (t == 0) { s_bofs = pre; s_tot = v; }
    }

    const int base = blockIdx.x * 1024 + t * 4;
    int v[4];
    int local = 0;
#pragma unroll
    for (int i = 0; i < 4; ++i) {
        int idx = base + i;
        v[i] = (idx < N) ? cnt[idx] : 0;
        local += v[i];
    }
    sums[t] = local;
    __syncthreads();
    for (int off = 1; off < 256; off <<= 1) {
        int u = (t >= off) ? sums[t - off] : 0;
        __syncthreads();
        sums[t] += u;
        __syncthreads();
    }
    int run = s_bofs + sums[t] - local;  // exclusive thread offset
#pragma unroll
    for (int i = 0; i < 4; ++i) {
        int idx = base + i;
        if (idx < N) {
            row_ptr[idx] = run;
            cursor[idx] = run;
            dinv[idx] = rsqrtf(1.0f + (float)v[i]);  // +1 self-loop
        }
        run += v[i];
    }
    if (blockIdx.x == NBLK - 1 && t == 0) row_ptr[N] = s_tot;  // == E
}

__global__ __launch_bounds__(256) void k_permute(const int* __restrict__ src,
                                                 const int* __restrict__ dst,
                                                 int* __restrict__ cursor,
                                                 int* __restrict__ srcs) {
    int e = blockIdx.x * 256 + threadIdx.x;
    if (e < E) {
        int pos = atomicAdd(&cursor[dst[e]], 1);
        srcs[pos] = src[e];
    }
}

// ---------------- GEMM 1 (MFMA, split-bf16 x3): [N,512]@[512,256] ---------------
// ROUND 13. R12 (lb(256,8)) was a disaster: gfx950's UNIFIED VGPR+AGPR file means
// this kernel needs ~96 regs/wave (64 V + 32 AGPR acc); forcing 8 waves/SIMD
// squeezed arch VGPRs to 32 and spilled (WRITE_SIZE 25->835MB, 5x slower).
// Occupancy math must use V+A. Revert to the R11 known-good config (79us).
// NEW: the limiting pipe at 79us is the VMEM instruction stream: 40 wave-instrs
// x 1KB per block-iter (8 A-staging + 32 B register loads), B loaded twice per
// block (both wr waves). FIX: stage B through LDS. For fixed ktg the 8 ntg tiles
// are 16KB CONTIGUOUS in Wf -> 16 linear global_load_lds chunks, double-buffered;
// both wr waves read frags via conflict-free ds_read_b128. VMEM instrs 40->24,
// L1 B-bytes halved, B consumption moves to the LDS pipe (parallel to VMEM).
// LDS 16(A)+32(B)=48KB -> 3 blocks/CU, lb(256,3) (reg target 170, no spill).
// (R8: no deeper reg pipeline. R11: issue order alone is a null. R12: V+A budget.)

__device__ inline void split_pair(float x0, float x1, unsigned& hp, unsigned& lp) {
    unsigned u0 = __float_as_uint(x0), u1 = __float_as_uint(x1);
    unsigned h0 = u0 & 0xffff0000u, h1 = u1 & 0xffff0000u;
    float l0 = x0 - __uint_as_float(h0);
    float l1 = x1 - __uint_as_float(h1);
    hp = __builtin_amdgcn_perm(u1, u0, 0x07060302u);  // [u0.hi16, u1.hi16]
    lp = __builtin_amdgcn_perm(__float_as_uint(l1), __float_as_uint(l0), 0x07060302u);
}

__device__ inline void split_frag(const float4& a, const float4& b, short8& hi, short8& lo) {
    unsigned h0, h1, h2, h3, l0, l1, l2, l3;
    split_pair(a.x, a.y, h0, l0);
    split_pair(a.z, a.w, h1, l1);
    split_pair(b.x, b.y, h2, l2);
    split_pair(b.z, b.w, h3, l3);
    uint4v h, l;
    h[0] = h0; h[1] = h1; h[2] = h2; h[3] = h3;
    l[0] = l0; l[1] = l1; l[2] = l2; l[3] = l3;
    hi = __builtin_bit_cast(short8, h);
    lo = __builtin_bit_cast(short8, l);
}

// Stage one 64-row x 32-col fp32 X tile into LDS (8 KB), XOR-swizzled.
// Chunk q in [0,512): row = q>>3, slot = q&7; LDS byte = q*16 (linear, as
// global_load_lds requires); source granule = slot ^ (row&7) (involution).
// Rows past N are redirected to row 0 (their acc is never stored).
__device__ inline void stage_x_tile(const float* __restrict__ X, int brow, int k0,
                                    float* lds, int tid) {
    const int wbase = tid & ~63;  // wave-uniform chunk base
#pragma unroll
    for (int c = 0; c < 2; ++c) {
        int q = c * 256 + tid;
        int row = q >> 3;
        int gc = ((q & 7) ^ (row & 7)) << 2;  // swizzled source col (floats)
        int r = brow + row;
        const float* src = X + (size_t)(r < N ? r : 0) * FIN + k0 + gc;
        float* dst = lds + (size_t)(c * 256 + wbase) * 4;  // wave-uniform, lane adds 16B
        __builtin_amdgcn_global_load_lds((const __attribute__((address_space(1))) void*)src,
                                         (__attribute__((address_space(3))) void*)dst,
                                         16, 0, 0);
    }
}

// Stage this block's 16 KB B-slab for K-tile ktg (8 ntg tiles x hi/lo, contiguous
// in Wf) into LDS. 16 chunks of 1 KB; wave w covers chunks w*4..w*4+3.
__device__ inline void stage_b_tile(const unsigned short* __restrict__ Wf, int ktg, int colb,
                                    unsigned short* lds, int w, int l) {
    const unsigned short* base = Wf + (size_t)(ktg * 16 + colb * 8) * 1024;
#pragma unroll
    for (int c = 0; c < 4; ++c) {
        int m = w * 4 + c;
        const unsigned short* src = base + m * 512 + l * 8;  // per-lane global addr
        unsigned short* dst = lds + m * 512;                 // wave-uniform, lane adds 16B
        __builtin_amdgcn_global_load_lds((const __attribute__((address_space(1))) void*)src,
                                         (__attribute__((address_space(3))) void*)dst,
                                         16, 0, 0);
    }
}

__global__ __launch_bounds__(256, 3) void k_gemm1_mfma(const float* __restrict__ X,
                                                       const unsigned short* __restrict__ Wf,
                                                       const float* __restrict__ dinv,
                                                       unsigned short* __restrict__ Hout) {
    __shared__ float As[2][2048];            // 2 x (64 rows x 32 cols) fp32 = 16 KB
    __shared__ unsigned short Bs[2][8192];   // 2 x 16 KB B slab = 32 KB
    const int tid = threadIdx.x;
    const int w = tid >> 6, l = tid & 63;
    const int wr = w >> 1, wc = w & 1;        // wave: 32-row group x 64-col group
    const int brow = blockIdx.x * 64;         // block row base
    const int row0 = brow + wr * 32;          // this wave's global row base
    const int wrow = wr * 32;                 // this wave's LDS-local row base
    const int colb = blockIdx.y;
    const int lm = l & 15;
    const int lk2 = (l >> 4) * 2;             // fragment granule pair base (16B units)

    f32x4 acc[2][4];
#pragma unroll
    for (int i = 0; i < 2; ++i)
#pragma unroll
        for (int j = 0; j < 4; ++j) acc[i][j] = (f32x4)0.f;

    // prologue: stage K-tile 0 (A and B)
    stage_x_tile(X, brow, 0, As[0], tid);
    stage_b_tile(Wf, 0, colb, Bs[0], w, l);

    for (int ktg = 0; ktg < 16; ++ktg) {
        const int cur = ktg & 1;
        __syncthreads();  // drains vmcnt(0): As[cur] / Bs[cur] staged & visible

        // stage next K-tile (completes during MFMA phase, drained at next barrier)
        if (ktg < 15) {
            stage_x_tile(X, brow, (ktg + 1) * 32, As[cur ^ 1], tid);
            stage_b_tile(Wf, ktg + 1, colb, Bs[cur ^ 1], w, l);
        }

        // B frags from LDS (ds_read_b128, lane-contiguous, conflict-free)
        const unsigned short* bb = Bs[cur] + (size_t)(wc * 4) * 1024 + (size_t)l * 8;
        short8 Bh[4], Bl[4];
#pragma unroll
        for (int j = 0; j < 4; ++j) {
            Bh[j] = *(const short8*)(bb + j * 1024);
            Bl[j] = *(const short8*)(bb + j * 1024 + 512);
        }

        // A frags from LDS (swizzled ds_read_b128), then fp32 -> bf16 hi/lo split
        short8 Ah[2], Al[2];
        const float* Ab = As[cur];
#pragma unroll
        for (int i = 0; i < 2; ++i) {
            int row = wrow + i * 16 + lm;
            const float* rbp = Ab + row * 32;
            int p = row & 7;
            float4 a0 = *(const float4*)(rbp + ((lk2 ^ p) << 2));
            float4 a1 = *(const float4*)(rbp + (((lk2 + 1) ^ p) << 2));
            split_frag(a0, a1, Ah[i], Al[i]);
        }

        // MFMA: 2x4 16x16 tiles, 3 split terms (AhBh + AhBl + AlBh)
#pragma unroll
        for (int i = 0; i < 2; ++i)
#pragma unroll
            for (int j = 0; j < 4; ++j) {
                acc[i][j] = __builtin_amdgcn_mfma_f32_16x16x32_bf16(Ah[i], Bh[j], acc[i][j], 0, 0, 0);
                acc[i][j] = __builtin_amdgcn_mfma_f32_16x16x32_bf16(Ah[i], Bl[j], acc[i][j], 0, 0, 0);
                acc[i][j] = __builtin_amdgcn_mfma_f32_16x16x32_bf16(Al[i], Bh[j], acc[i][j], 0, 0, 0);
            }
    }

    // ---- epilogue: C row = (l>>4)*4 + reg, col = l&15 ; *dinv[row], store bf16 ----
    const int col0 = colb * 128 + wc * 64;
#pragma unroll
    for (int i = 0; i < 2; ++i) {
        int rbase = row0 + i * 16 + (l >> 4) * 4;
        float dv[4];
        bool okr[4];
#pragma unroll
        for (int r = 0; r < 4; ++r) {
            int rr = rbase + r;
            okr[r] = rr < N;
            dv[r] = okr[r] ? dinv[rr] : 0.f;
        }
#pragma unroll
        for (int j = 0; j < 4; ++j) {
            int col = col0 + j * 16 + lm;
#pragma unroll
            for (int r = 0; r < 4; ++r)
                if (okr[r]) Hout[(size_t)(rbase + r) * H1v + col] = f2bf(acc[i][j][r] * dv[r]);
        }
    }
}

// ---------------- GEMM 2: [N,256] @ [256,32] fp32 in, *dinv, bf16 out ----------------

__global__ __launch_bounds__(256) void k_gemm2(const float* __restrict__ A,
                                               const float* __restrict__ W,
                                               const float* __restrict__ dinv,
                                               unsigned short* __restrict__ Hout) {
    __shared__ float Ws[H1v * H2v];  // 32 KB
    const int tid = threadIdx.x;
#pragma unroll
    for (int i = 0; i < 8; ++i) {
        int off = tid * 4 + i * 1024;
        *(float4*)(&Ws[off]) = *(const float4*)(W + off);
    }
    __syncthreads();

    const int row = blockIdx.x * 8 + (tid >> 5);
    const int col = tid & 31;
    if (row >= N) return;
    const float* arow = A + (size_t)row * H1v;
    float sum = 0.f;
#pragma unroll 4
    for (int k = 0; k < H1v; k += 4) {
        float4 a4 = *(const float4*)(arow + k);
        sum = fmaf(a4.x, Ws[(k + 0) * H2v + col], sum);
        sum = fmaf(a4.y, Ws[(k + 1) * H2v + col], sum);
        sum = fmaf(a4.z, Ws[(k + 2) * H2v + col], sum);
        sum = fmaf(a4.w, Ws[(k + 3) * H2v + col], sum);
    }
    Hout[(size_t)row * H2v + col] = f2bf(sum * dinv[row]);
}

// ---------------- CSR aggregation (atomic-free, bf16 messages, fp32 accum) -------
// h holds bf16 h'[i] = dinv[i]*(a@W)[i].  out[d] = dinv[d]*(sum h'[s] + h'[d]) + b

__global__ __launch_bounds__(256) void k_agg_d256(const unsigned short* __restrict__ h,
                                                  const int* __restrict__ rp,
                                                  const int* __restrict__ srcs,
                                                  const float* __restrict__ dinv,
                                                  const float* __restrict__ bias,
                                                  float* __restrict__ out) {
    const int wave = threadIdx.x >> 6;
    const int lane = threadIdx.x & 63;
    const int d = blockIdx.x * 4 + wave;
    if (d >= N) return;
    const int beg = rp[d], end = rp[d + 1];
    const int fo = lane * 4;
    us4 sv = *(const us4*)(h + (size_t)d * H1v + fo);  // self-loop
    float ax = bf2f(sv.x), ay = bf2f(sv.y), az = bf2f(sv.z), aw = bf2f(sv.w);
    int j = beg;
    for (; j + 3 < end; j += 4) {  // 4 independent gathers in flight
        int s0 = srcs[j], s1 = srcs[j + 1], s2 = srcs[j + 2], s3 = srcs[j + 3];
        us4 v0 = *(const us4*)(h + (size_t)s0 * H1v + fo);
        us4 v1 = *(const us4*)(h + (size_t)s1 * H1v + fo);
        us4 v2 = *(const us4*)(h + (size_t)s2 * H1v + fo);
        us4 v3 = *(const us4*)(h + (size_t)s3 * H1v + fo);
        ax += bf2f(v0.x) + bf2f(v1.x) + bf2f(v2.x) + bf2f(v3.x);
        ay += bf2f(v0.y) + bf2f(v1.y) + bf2f(v2.y) + bf2f(v3.y);
        az += bf2f(v0.z) + bf2f(v1.z) + bf2f(v2.z) + bf2f(v3.z);
        aw += bf2f(v0.w) + bf2f(v1.w) + bf2f(v2.w) + bf2f(v3.w);
    }
    for (; j < end; ++j) {
        us4 v = *(const us4*)(h + (size_t)srcs[j] * H1v + fo);
        ax += bf2f(v.x); ay += bf2f(v.y); az += bf2f(v.z); aw += bf2f(v.w);
    }
    const float di = dinv[d];
    const float4 b4 = *(const float4*)(bias + fo);
    float4 o;
    o.x = fmaxf(fmaf(di, ax, b4.x), 0.f);
    o.y = fmaxf(fmaf(di, ay, b4.y), 0.f);
    o.z = fmaxf(fmaf(di, az, b4.z), 0.f);
    o.w = fmaxf(fmaf(di, aw, b4.w), 0.f);
    *(float4*)(out + (size_t)d * H1v + fo) = o;
}

// ---------------- fused: agg over h2 (D=32) + GEMM3 [32x16] -> h3 bf16 ----------
// Block = 8 dst rows. Phase 1: thread (sub,f) aggregates row sub, dim f; a2 row
// (relu(dinv*sum+b2)) goes to LDS (padded stride 33). Phase 2: threads 0..127
// compute 8x16 GEMM3 outputs from LDS, *dinv, store bf16. Kills the a2 buffer.

__global__ __launch_bounds__(256) void k_agg32_gemm3(const unsigned short* __restrict__ h2,
                                                     const int* __restrict__ rp,
                                                     const int* __restrict__ srcs,
                                                     const float* __restrict__ dinv,
                                                     const float* __restrict__ b2,
                                                     const float* __restrict__ W3,
                                                     unsigned short* __restrict__ h3) {
    __shared__ float als[8][33];       // +1 pad: kills 4-way stride-32 conflicts
    __shared__ float W3s[H2v * Cv];    // 512 floats
    const int t = threadIdx.x;
    *(float2*)(&W3s[t * 2]) = *(const float2*)(W3 + t * 2);

    const int sub = t >> 5, f = t & 31;
    const int d = blockIdx.x * 8 + sub;  // N % 8 == 0
    const int beg = rp[d], end = rp[d + 1];
    float acc = bf2f(h2[(size_t)d * H2v + f]);  // self-loop
    int j = beg;
    for (; j + 3 < end; j += 4) {
        float v0 = bf2f(h2[(size_t)srcs[j] * H2v + f]);
        float v1 = bf2f(h2[(size_t)srcs[j + 1] * H2v + f]);
        float v2 = bf2f(h2[(size_t)srcs[j + 2] * H2v + f]);
        float v3 = bf2f(h2[(size_t)srcs[j + 3] * H2v + f]);
        acc += v0 + v1 + v2 + v3;
    }
    for (; j < end; ++j) acc += bf2f(h2[(size_t)srcs[j] * H2v + f]);
    als[sub][f] = fmaxf(fmaf(dinv[d], acc, b2[f]), 0.f);
    __syncthreads();

    if (t < 128) {
        const int row = t >> 4, col = t & 15;
        float sum = 0.f;
#pragma unroll
        for (int k = 0; k < H2v; ++k) sum = fmaf(als[row][k], W3s[k * Cv + col], sum);
        const int gr = blockIdx.x * 8 + row;
        h3[(size_t)gr * Cv + col] = f2bf(sum * dinv[gr]);
    }
}

// ---------------- final aggregation over h3 (D=16) -> out fp32 ----------------

__global__ __launch_bounds__(256) void k_agg16(const unsigned short* __restrict__ h,
                                               const int* __restrict__ rp,
                                               const int* __restrict__ srcs,
                                               const float* __restrict__ dinv,
                                               const float* __restrict__ bias,
                                               float* __restrict__ out) {
    const int sub = threadIdx.x >> 4;
    const int f = threadIdx.x & 15;
    const int d = blockIdx.x * 16 + sub;
    if (d >= N) return;
    const int beg = rp[d], end = rp[d + 1];
    float acc = bf2f(h[(size_t)d * Cv + f]);  // self-loop
    int j = beg;
    for (; j + 3 < end; j += 4) {
        float v0 = bf2f(h[(size_t)srcs[j] * Cv + f]);
        float v1 = bf2f(h[(size_t)srcs[j + 1] * Cv + f]);
        float v2 = bf2f(h[(size_t)srcs[j + 2] * Cv + f]);
        float v3 = bf2f(h[(size_t)srcs[j + 3] * Cv + f]);
        acc += v0 + v1 + v2 + v3;
    }
    for (; j < end; ++j) acc += bf2f(h[(size_t)srcs[j] * Cv + f]);
    out[(size_t)d * Cv + f] = fmaf(dinv[d], acc, bias[f]);
}

// ---------------- launch ----------------

extern "C" void kernel_launch(void* const* d_in, const int* in_sizes, int n_in,
                              void* d_out, int out_size, void* d_ws, size_t ws_size,
                              hipStream_t stream) {
    const float* x  = (const float*)d_in[0];
    const int*   ei = (const int*)d_in[1];
    const float* W1 = (const float*)d_in[2];
    const float* b1 = (const float*)d_in[3];
    const float* W2 = (const float*)d_in[4];
    const float* b2 = (const float*)d_in[5];
    const float* W3 = (const float*)d_in[6];
    const float* b3 = (const float*)d_in[7];
    const int* src = ei;       // edge_index[0]
    const int* dst = ei + E;   // edge_index[1]
    float* out = (float*)d_out;

    // Workspace layout (bytes):
    // [0       ] dinv    float[50000]
    // [0x40000 ] cnt/rp  int[50001]   (in-place scan)
    // [0x80000 ] cursor  int[50000]
    // [0xB2000 ] bsum    int[49]
    // [0xC0000 ] srcs    int[800000]
    // [4 MiB   ] Wsplit  ushort[262144]  (512 KB)
    // [5 MiB   ] h1 bf16, a1 fp32, h2 bf16, h3 bf16   (a2 eliminated)
    char* ws = (char*)d_ws;
    float* dinv   = (float*)ws;
    int*   cnt    = (int*)(ws + 0x40000);
    int*   rp     = cnt;
    int*   cursor = (int*)(ws + 0x80000);
    int*   bsum   = (int*)(ws + 0xB2000);
    int*   srcs   = (int*)(ws + 0xC0000);
    unsigned short* wsplit = (unsigned short*)(ws + (size_t)4 * 1024 * 1024);
    char* p = ws + (size_t)5 * 1024 * 1024;
    unsigned short* h1 = (unsigned short*)p; p += (size_t)N * H1v * sizeof(unsigned short);
    float*          a1 = (float*)p;          p += (size_t)N * H1v * sizeof(float);
    unsigned short* h2 = (unsigned short*)p; p += (size_t)N * H2v * sizeof(unsigned short);
    unsigned short* h3 = (unsigned short*)p;

    // CSR build + weight split: 5 dispatches
    k_init<<<64 + (N + 256) / 256, 256, 0, stream>>>(W1, wsplit, cnt);
    k_hist<<<(E + 255) / 256, 256, 0, stream>>>(dst, cnt);
    k_scan_part<<<NBLK, 256, 0, stream>>>(cnt, bsum);
    k_scan_final<<<NBLK, 256, 0, stream>>>(cnt, bsum, rp, cursor, dinv);
    k_permute<<<(E + 255) / 256, 256, 0, stream>>>(src, dst, cursor, srcs);

    // ---- layer 1: 512 -> 256 (MFMA, LDS-staged A+B double-buffer, 64x128 tiles), ReLU ----
    dim3 g1((N + 63) / 64, 2);
    k_gemm1_mfma<<<g1, 256, 0, stream>>>(x, wsplit, dinv, h1);
    k_agg_d256<<<(N + 3) / 4, 256, 0, stream>>>(h1, rp, srcs, dinv, b1, a1);

    // ---- layer 2: 256 -> 32, ReLU ----
    k_gemm2<<<N / 8, 256, 0, stream>>>(a1, W2, dinv, h2);

    // ---- fused: agg(h2) + GEMM3 -> h3 ----
    k_agg32_gemm3<<<N / 8, 256, 0, stream>>>(h2, rp, srcs, dinv, b2, W3, h3);

    // ---- final aggregation -> out ----
    k_agg16<<<(N + 15) / 16, 256, 0, stream>>>(h3, rp, srcs, dinv, b3, out);
}

// Round 6
// 436.463 us; speedup vs baseline: 1.7907x; 1.0287x over previous
//
#include <hip/hip_runtime.h>

// Problem constants (from reference)
constexpr int N   = 50000;
constexpr int E   = 800000;
constexpr int FIN = 512;
constexpr int H1v = 256;
constexpr int H2v = 32;
constexpr int Cv  = 16;

constexpr int NBLK = (N + 1023) / 1024;  // 49 scan blocks

typedef __attribute__((ext_vector_type(8))) short short8;            // 8 bf16 (MFMA frag)
typedef __attribute__((ext_vector_type(4))) float f32x4;             // MFMA C/D frag
typedef __attribute__((ext_vector_type(4))) unsigned short us4;      // 4 bf16
typedef __attribute__((ext_vector_type(4))) unsigned int uint4v;

// fp32 -> bf16 round-to-nearest-even, and back
__device__ inline unsigned short f2bf(float f) {
    unsigned u = __float_as_uint(f);
    return (unsigned short)((u + 0x7FFFu + ((u >> 16) & 1u)) >> 16);
}
__device__ inline float bf2f(unsigned short b) { return __uint_as_float(((unsigned)b) << 16); }

// ---------------- init: cnt zeroing + W1 split, fused (independent data) --------
// Blocks 0..63: W1 split into bf16 hi/lo MFMA B-frag layout.
// Blocks 64.. : cnt[0..N] = 0.
// W-frag layout: tile (ktg 0..15, ntg 0..15): B[k][n], k=ktg*32+(l>>4)*8+j,
// n=ntg*16+(l&15); tile base = ((ktg*16+ntg)*2)*512; hi at +l*8, lo at +512+l*8.

__global__ __launch_bounds__(256) void k_init(const float* __restrict__ W,
                                              unsigned short* __restrict__ Wf,
                                              int* __restrict__ cnt) {
    const int b = blockIdx.x;
    if (b < 64) {
        int t = b * 256 + threadIdx.x;  // 0..16383
        int l = t & 63, nt = (t >> 6) & 15, kt = t >> 10;
        int n = nt * 16 + (l & 15);
        int kb = kt * 32 + (l >> 4) * 8;
        short8 h8, l8;
#pragma unroll
        for (int j = 0; j < 8; ++j) {
            float w = W[(size_t)(kb + j) * H1v + n];
            unsigned short h = f2bf(w);
            h8[j] = (short)h;
            l8[j] = (short)f2bf(w - bf2f(h));
        }
        size_t base = ((size_t)(kt * 16 + nt) * 2) * 512 + (size_t)l * 8;
        *(short8*)(Wf + base) = h8;
        *(short8*)(Wf + base + 512) = l8;
    } else {
        int i = (b - 64) * 256 + threadIdx.x;
        if (i <= N) cnt[i] = 0;
    }
}

// ---------------- degree histogram / CSR build ----------------

__global__ __launch_bounds__(256) void k_hist(const int* __restrict__ dst,
                                              int* __restrict__ cnt) {
    int e = blockIdx.x * 256 + threadIdx.x;
    if (e < E) atomicAdd(&cnt[dst[e]], 1);
}

// Phase 1: per-block (1024 elems) sums.
__global__ __launch_bounds__(256) void k_scan_part(const int* __restrict__ cnt,
                                                   int* __restrict__ bsum) {
    __shared__ int red[256];
    const int t = threadIdx.x;
    const int base = blockIdx.x * 1024 + t * 4;
    int s = 0;
#pragma unroll
    for (int i = 0; i < 4; ++i) {
        int idx = base + i;
        if (idx < N) s += cnt[idx];
    }
    red[t] = s;
    __syncthreads();
    for (int off = 128; off > 0; off >>= 1) {
        if (t < off) red[t] += red[t + off];
        __syncthreads();
    }
    if (t == 0) bsum[blockIdx.x] = red[0];
}

// Phase 2 (fused top + final): block offset computed in-block from bsum (49 ints,
// one wave), then block-local scan -> row_ptr, cursor, dinv. In-place safe vs cnt:
// each block reads only its own disjoint 1024-range into registers before writes.
__global__ __launch_bounds__(256) void k_scan_final(const int* __restrict__ cnt,
                                                    const int* __restrict__ bsum,
                                                    int* __restrict__ row_ptr,
                                                    int* __restrict__ cursor,
                                                    float* __restrict__ dinv) {
    __shared__ int sums[256];
    __shared__ int s_bofs, s_tot;
    const int t = threadIdx.x;

    if (t < 64) {  // one wave: prefix-of-my-block + grand total over bsum[49]
        int v = (t < NBLK) ? bsum[t] : 0;
        int pre = (t < (int)blockIdx.x) ? v : 0;
#pragma unroll
        for (int off = 32; off > 0; off >>= 1) {
            pre += __shfl_down(pre, off, 64);
            v   += __shfl_down(v, off, 64);
        }
        if (t == 0) { s_bofs = pre; s_tot = v; }
    }

    const int base = blockIdx.x * 1024 + t * 4;
    int v[4];
    int local = 0;
#pragma unroll
    for (int i = 0; i < 4; ++i) {
        int idx = base + i;
        v[i] = (idx < N) ? cnt[idx] : 0;
        local += v[i];
    }
    sums[t] = local;
    __syncthreads();
    for (int off = 1; off < 256; off <<= 1) {
        int u = (t >= off) ? sums[t - off] : 0;
        __syncthreads();
        sums[t] += u;
        __syncthreads();
    }
    int run = s_bofs + sums[t] - local;  // exclusive thread offset
#pragma unroll
    for (int i = 0; i < 4; ++i) {
        int idx = base + i;
        if (idx < N) {
            row_ptr[idx] = run;
            cursor[idx] = run;
            dinv[idx] = rsqrtf(1.0f + (float)v[i]);  // +1 self-loop
        }
        run += v[i];
    }
    if (blockIdx.x == NBLK - 1 && t == 0) row_ptr[N] = s_tot;  // == E
}

__global__ __launch_bounds__(256) void k_permute(const int* __restrict__ src,
                                                 const int* __restrict__ dst,
                                                 int* __restrict__ cursor,
                                                 int* __restrict__ srcs) {
    int e = blockIdx.x * 256 + threadIdx.x;
    if (e < E) {
        int pos = atomicAdd(&cursor[dst[e]], 1);
        srcs[pos] = src[e];
    }
}

// ---------------- GEMM 1 (MFMA, split-bf16 x3): [N,512]@[512,256] ---------------
// ROUND 14. Ledger: R9 A-staging null; R10 occupancy 2->4 blk/CU = -28%; R11
// issue-reorder null; R12 lb(256,8) spilled (V+A unified: ~96 regs/wave needed);
// R13 B-via-LDS regressed (48KB LDS -> 3 blk/CU, occupancy rules). Best = R11
// structure @79us. The residual stall is per-iteration fixed cost (barrier skew,
// B vmcnt wait ~400cy, staging drain ~400cy, lgkm) paid 16x per block.
// THIS ROUND: BK=64 — two MFMA sub-steps per barrier. Iterations 16->8, all
// fixed costs halve, MFMA latency-cover per iter doubles (932cy). LDS stays
// 32KB (2 x 64x64 fp32 dbuf) -> still 4 blk/CU at lb(256,4). Register care
// (R12): B sub-tile register sets sequenced (B1 issued just before MFMA0 so B0's
// regs die into B1) to stay under the 128 V+A budget. Tripwire: WRITE_SIZE jump
// = spill = revert.

__device__ inline void split_pair(float x0, float x1, unsigned& hp, unsigned& lp) {
    unsigned u0 = __float_as_uint(x0), u1 = __float_as_uint(x1);
    unsigned h0 = u0 & 0xffff0000u, h1 = u1 & 0xffff0000u;
    float l0 = x0 - __uint_as_float(h0);
    float l1 = x1 - __uint_as_float(h1);
    hp = __builtin_amdgcn_perm(u1, u0, 0x07060302u);  // [u0.hi16, u1.hi16]
    lp = __builtin_amdgcn_perm(__float_as_uint(l1), __float_as_uint(l0), 0x07060302u);
}

__device__ inline void split_frag(const float4& a, const float4& b, short8& hi, short8& lo) {
    unsigned h0, h1, h2, h3, l0, l1, l2, l3;
    split_pair(a.x, a.y, h0, l0);
    split_pair(a.z, a.w, h1, l1);
    split_pair(b.x, b.y, h2, l2);
    split_pair(b.z, b.w, h3, l3);
    uint4v h, l;
    h[0] = h0; h[1] = h1; h[2] = h2; h[3] = h3;
    l[0] = l0; l[1] = l1; l[2] = l2; l[3] = l3;
    hi = __builtin_bit_cast(short8, h);
    lo = __builtin_bit_cast(short8, l);
}

// Stage one 64-row x 64-col fp32 X tile into LDS (16 KB), XOR-swizzled.
// Chunk q in [0,1024): row = q>>4, slot = q&15; LDS byte = q*16 (linear, as
// global_load_lds requires); source granule = slot ^ (row&15) (involution).
// Rows past N are redirected to row 0 (their acc is never stored).
__device__ inline void stage_x_tile(const float* __restrict__ X, int brow, int k0,
                                    float* lds, int tid) {
    const int wbase = tid & ~63;  // wave-uniform chunk base
#pragma unroll
    for (int c = 0; c < 4; ++c) {
        int q = c * 256 + tid;
        int row = q >> 4;
        int gc = ((q & 15) ^ (row & 15)) << 2;  // swizzled source col (floats)
        int r = brow + row;
        const float* src = X + (size_t)(r < N ? r : 0) * FIN + k0 + gc;
        float* dst = lds + (size_t)(c * 256 + wbase) * 4;  // wave-uniform, lane adds 16B
        __builtin_amdgcn_global_load_lds((const __attribute__((address_space(1))) void*)src,
                                         (__attribute__((address_space(3))) void*)dst,
                                         16, 0, 0);
    }
}

__global__ __launch_bounds__(256, 4) void k_gemm1_mfma(const float* __restrict__ X,
                                                       const unsigned short* __restrict__ Wf,
                                                       const float* __restrict__ dinv,
                                                       unsigned short* __restrict__ Hout) {
    __shared__ float As[2][4096];  // 2 x (64 rows x 64 cols) fp32 = 32 KB
    const int tid = threadIdx.x;
    const int w = tid >> 6, l = tid & 63;
    const int wr = w >> 1, wc = w & 1;        // wave: 32-row group x 64-col group
    const int brow = blockIdx.x * 64;         // block row base
    const int row0 = brow + wr * 32;          // this wave's global row base
    const int wrow = wr * 32;                 // this wave's LDS-local row base
    const int colb = blockIdx.y;
    const int lm = l & 15;
    const int lk2 = (l >> 4) * 2;             // fragment granule pair base (16B units)

    // B frag lane pointer (tiles ntg = colb*8 + wc*4 + j)
    const unsigned short* bp0 = Wf + (size_t)(colb * 8 + wc * 4) * 1024 + (size_t)l * 8;

    f32x4 acc[2][4];
#pragma unroll
    for (int i = 0; i < 2; ++i)
#pragma unroll
        for (int j = 0; j < 4; ++j) acc[i][j] = (f32x4)0.f;

    // prologue: stage K-tile 0 (64 cols)
    stage_x_tile(X, brow, 0, As[0], tid);

    for (int kt = 0; kt < 8; ++kt) {
        const int cur = kt & 1;
        __syncthreads();  // drains vmcnt(0): As[cur] staged & visible

        // B frags for sub-step 0 (ktg = 2*kt), L2-hot frag layout
        const unsigned short* bpA = bp0 + (size_t)(2 * kt) * 16384;
        short8 B0h[4], B0l[4];
#pragma unroll
        for (int j = 0; j < 4; ++j) {
            B0h[j] = *(const short8*)(bpA + j * 1024);
            B0l[j] = *(const short8*)(bpA + j * 1024 + 512);
        }

        // stage next 64-col K-tile (completes during the two MFMA phases)
        if (kt < 7) stage_x_tile(X, brow, (kt + 1) * 64, As[cur ^ 1], tid);

        const float* Ab = As[cur];

        // ---- sub-step 0: granules [0,8) ----
        short8 Ah[2], Al[2];
#pragma unroll
        for (int i = 0; i < 2; ++i) {
            int row = wrow + i * 16 + lm;
            const float* rbp = Ab + row * 64;
            int p = row & 15;
            float4 a0 = *(const float4*)(rbp + ((lk2 ^ p) << 2));
            float4 a1 = *(const float4*)(rbp + (((lk2 + 1) ^ p) << 2));
            split_frag(a0, a1, Ah[i], Al[i]);
        }

        // B frags for sub-step 1 issued BEFORE MFMA block 0 (latency covered by it)
        const unsigned short* bpB = bpA + 16384;
        short8 B1h[4], B1l[4];
#pragma unroll
        for (int j = 0; j < 4; ++j) {
            B1h[j] = *(const short8*)(bpB + j * 1024);
            B1l[j] = *(const short8*)(bpB + j * 1024 + 512);
        }

#pragma unroll
        for (int i = 0; i < 2; ++i)
#pragma unroll
            for (int j = 0; j < 4; ++j) {
                acc[i][j] = __builtin_amdgcn_mfma_f32_16x16x32_bf16(Ah[i], B0h[j], acc[i][j], 0, 0, 0);
                acc[i][j] = __builtin_amdgcn_mfma_f32_16x16x32_bf16(Ah[i], B0l[j], acc[i][j], 0, 0, 0);
                acc[i][j] = __builtin_amdgcn_mfma_f32_16x16x32_bf16(Al[i], B0h[j], acc[i][j], 0, 0, 0);
            }

        // ---- sub-step 1: granules [8,16) ----
#pragma unroll
        for (int i = 0; i < 2; ++i) {
            int row = wrow + i * 16 + lm;
            const float* rbp = Ab + row * 64;
            int p = row & 15;
            int g0 = lk2 + 8;
            float4 a0 = *(const float4*)(rbp + ((g0 ^ p) << 2));
            float4 a1 = *(const float4*)(rbp + (((g0 + 1) ^ p) << 2));
            split_frag(a0, a1, Ah[i], Al[i]);
        }

#pragma unroll
        for (int i = 0; i < 2; ++i)
#pragma unroll
            for (int j = 0; j < 4; ++j) {
                acc[i][j] = __builtin_amdgcn_mfma_f32_16x16x32_bf16(Ah[i], B1h[j], acc[i][j], 0, 0, 0);
                acc[i][j] = __builtin_amdgcn_mfma_f32_16x16x32_bf16(Ah[i], B1l[j], acc[i][j], 0, 0, 0);
                acc[i][j] = __builtin_amdgcn_mfma_f32_16x16x32_bf16(Al[i], B1h[j], acc[i][j], 0, 0, 0);
            }
    }

    // ---- epilogue: C row = (l>>4)*4 + reg, col = l&15 ; *dinv[row], store bf16 ----
    const int col0 = colb * 128 + wc * 64;
#pragma unroll
    for (int i = 0; i < 2; ++i) {
        int rbase = row0 + i * 16 + (l >> 4) * 4;
        float dv[4];
        bool okr[4];
#pragma unroll
        for (int r = 0; r < 4; ++r) {
            int rr = rbase + r;
            okr[r] = rr < N;
            dv[r] = okr[r] ? dinv[rr] : 0.f;
        }
#pragma unroll
        for (int j = 0; j < 4; ++j) {
            int col = col0 + j * 16 + lm;
#pragma unroll
            for (int r = 0; r < 4; ++r)
                if (okr[r]) Hout[(size_t)(rbase + r) * H1v + col] = f2bf(acc[i][j][r] * dv[r]);
        }
    }
}

// ---------------- GEMM 2: [N,256] @ [256,32] fp32 in, *dinv, bf16 out ----------------

__global__ __launch_bounds__(256) void k_gemm2(const float* __restrict__ A,
                                               const float* __restrict__ W,
                                               const float* __restrict__ dinv,
                                               unsigned short* __restrict__ Hout) {
    __shared__ float Ws[H1v * H2v];  // 32 KB
    const int tid = threadIdx.x;
#pragma unroll
    for (int i = 0; i < 8; ++i) {
        int off = tid * 4 + i * 1024;
        *(float4*)(&Ws[off]) = *(const float4*)(W + off);
    }
    __syncthreads();

    const int row = blockIdx.x * 8 + (tid >> 5);
    const int col = tid & 31;
    if (row >= N) return;
    const float* arow = A + (size_t)row * H1v;
    float sum = 0.f;
#pragma unroll 4
    for (int k = 0; k < H1v; k += 4) {
        float4 a4 = *(const float4*)(arow + k);
        sum = fmaf(a4.x, Ws[(k + 0) * H2v + col], sum);
        sum = fmaf(a4.y, Ws[(k + 1) * H2v + col], sum);
        sum = fmaf(a4.z, Ws[(k + 2) * H2v + col], sum);
        sum = fmaf(a4.w, Ws[(k + 3) * H2v + col], sum);
    }
    Hout[(size_t)row * H2v + col] = f2bf(sum * dinv[row]);
}

// ---------------- CSR aggregation (atomic-free, bf16 messages, fp32 accum) -------
// h holds bf16 h'[i] = dinv[i]*(a@W)[i].  out[d] = dinv[d]*(sum h'[s] + h'[d]) + b

__global__ __launch_bounds__(256) void k_agg_d256(const unsigned short* __restrict__ h,
                                                  const int* __restrict__ rp,
                                                  const int* __restrict__ srcs,
                                                  const float* __restrict__ dinv,
                                                  const float* __restrict__ bias,
                                                  float* __restrict__ out) {
    const int wave = threadIdx.x >> 6;
    const int lane = threadIdx.x & 63;
    const int d = blockIdx.x * 4 + wave;
    if (d >= N) return;
    const int beg = rp[d], end = rp[d + 1];
    const int fo = lane * 4;
    us4 sv = *(const us4*)(h + (size_t)d * H1v + fo);  // self-loop
    float ax = bf2f(sv.x), ay = bf2f(sv.y), az = bf2f(sv.z), aw = bf2f(sv.w);
    int j = beg;
    for (; j + 3 < end; j += 4) {  // 4 independent gathers in flight
        int s0 = srcs[j], s1 = srcs[j + 1], s2 = srcs[j + 2], s3 = srcs[j + 3];
        us4 v0 = *(const us4*)(h + (size_t)s0 * H1v + fo);
        us4 v1 = *(const us4*)(h + (size_t)s1 * H1v + fo);
        us4 v2 = *(const us4*)(h + (size_t)s2 * H1v + fo);
        us4 v3 = *(const us4*)(h + (size_t)s3 * H1v + fo);
        ax += bf2f(v0.x) + bf2f(v1.x) + bf2f(v2.x) + bf2f(v3.x);
        ay += bf2f(v0.y) + bf2f(v1.y) + bf2f(v2.y) + bf2f(v3.y);
        az += bf2f(v0.z) + bf2f(v1.z) + bf2f(v2.z) + bf2f(v3.z);
        aw += bf2f(v0.w) + bf2f(v1.w) + bf2f(v2.w) + bf2f(v3.w);
    }
    for (; j < end; ++j) {
        us4 v = *(const us4*)(h + (size_t)srcs[j] * H1v + fo);
        ax += bf2f(v.x); ay += bf2f(v.y); az += bf2f(v.z); aw += bf2f(v.w);
    }
    const float di = dinv[d];
    const float4 b4 = *(const float4*)(bias + fo);
    float4 o;
    o.x = fmaxf(fmaf(di, ax, b4.x), 0.f);
    o.y = fmaxf(fmaf(di, ay, b4.y), 0.f);
    o.z = fmaxf(fmaf(di, az, b4.z), 0.f);
    o.w = fmaxf(fmaf(di, aw, b4.w), 0.f);
    *(float4*)(out + (size_t)d * H1v + fo) = o;
}

// ---------------- fused: agg over h2 (D=32) + GEMM3 [32x16] -> h3 bf16 ----------
// Block = 8 dst rows. Phase 1: thread (sub,f) aggregates row sub, dim f; a2 row
// (relu(dinv*sum+b2)) goes to LDS (padded stride 33). Phase 2: threads 0..127
// compute 8x16 GEMM3 outputs from LDS, *dinv, store bf16. Kills the a2 buffer.

__global__ __launch_bounds__(256) void k_agg32_gemm3(const unsigned short* __restrict__ h2,
                                                     const int* __restrict__ rp,
                                                     const int* __restrict__ srcs,
                                                     const float* __restrict__ dinv,
                                                     const float* __restrict__ b2,
                                                     const float* __restrict__ W3,
                                                     unsigned short* __restrict__ h3) {
    __shared__ float als[8][33];       // +1 pad: kills 4-way stride-32 conflicts
    __shared__ float W3s[H2v * Cv];    // 512 floats
    const int t = threadIdx.x;
    *(float2*)(&W3s[t * 2]) = *(const float2*)(W3 + t * 2);

    const int sub = t >> 5, f = t & 31;
    const int d = blockIdx.x * 8 + sub;  // N % 8 == 0
    const int beg = rp[d], end = rp[d + 1];
    float acc = bf2f(h2[(size_t)d * H2v + f]);  // self-loop
    int j = beg;
    for (; j + 3 < end; j += 4) {
        float v0 = bf2f(h2[(size_t)srcs[j] * H2v + f]);
        float v1 = bf2f(h2[(size_t)srcs[j + 1] * H2v + f]);
        float v2 = bf2f(h2[(size_t)srcs[j + 2] * H2v + f]);
        float v3 = bf2f(h2[(size_t)srcs[j + 3] * H2v + f]);
        acc += v0 + v1 + v2 + v3;
    }
    for (; j < end; ++j) acc += bf2f(h2[(size_t)srcs[j] * H2v + f]);
    als[sub][f] = fmaxf(fmaf(dinv[d], acc, b2[f]), 0.f);
    __syncthreads();

    if (t < 128) {
        const int row = t >> 4, col = t & 15;
        float sum = 0.f;
#pragma unroll
        for (int k = 0; k < H2v; ++k) sum = fmaf(als[row][k], W3s[k * Cv + col], sum);
        const int gr = blockIdx.x * 8 + row;
        h3[(size_t)gr * Cv + col] = f2bf(sum * dinv[gr]);
    }
}

// ---------------- final aggregation over h3 (D=16) -> out fp32 ----------------

__global__ __launch_bounds__(256) void k_agg16(const unsigned short* __restrict__ h,
                                               const int* __restrict__ rp,
                                               const int* __restrict__ srcs,
                                               const float* __restrict__ dinv,
                                               const float* __restrict__ bias,
                                               float* __restrict__ out) {
    const int sub = threadIdx.x >> 4;
    const int f = threadIdx.x & 15;
    const int d = blockIdx.x * 16 + sub;
    if (d >= N) return;
    const int beg = rp[d], end = rp[d + 1];
    float acc = bf2f(h[(size_t)d * Cv + f]);  // self-loop
    int j = beg;
    for (; j + 3 < end; j += 4) {
        float v0 = bf2f(h[(size_t)srcs[j] * Cv + f]);
        float v1 = bf2f(h[(size_t)srcs[j + 1] * Cv + f]);
        float v2 = bf2f(h[(size_t)srcs[j + 2] * Cv + f]);
        float v3 = bf2f(h[(size_t)srcs[j + 3] * Cv + f]);
        acc += v0 + v1 + v2 + v3;
    }
    for (; j < end; ++j) acc += bf2f(h[(size_t)srcs[j] * Cv + f]);
    out[(size_t)d * Cv + f] = fmaf(dinv[d], acc, bias[f]);
}

// ---------------- launch ----------------

extern "C" void kernel_launch(void* const* d_in, const int* in_sizes, int n_in,
                              void* d_out, int out_size, void* d_ws, size_t ws_size,
                              hipStream_t stream) {
    const float* x  = (const float*)d_in[0];
    const int*   ei = (const int*)d_in[1];
    const float* W1 = (const float*)d_in[2];
    const float* b1 = (const float*)d_in[3];
    const float* W2 = (const float*)d_in[4];
    const float* b2 = (const float*)d_in[5];
    const float* W3 = (const float*)d_in[6];
    const float* b3 = (const float*)d_in[7];
    const int* src = ei;       // edge_index[0]
    const int* dst = ei + E;   // edge_index[1]
    float* out = (float*)d_out;

    // Workspace layout (bytes):
    // [0       ] dinv    float[50000]
    // [0x40000 ] cnt/rp  int[50001]   (in-place scan)
    // [0x80000 ] cursor  int[50000]
    // [0xB2000 ] bsum    int[49]
    // [0xC0000 ] srcs    int[800000]
    // [4 MiB   ] Wsplit  ushort[262144]  (512 KB)
    // [5 MiB   ] h1 bf16, a1 fp32, h2 bf16, h3 bf16   (a2 eliminated)
    char* ws = (char*)d_ws;
    float* dinv   = (float*)ws;
    int*   cnt    = (int*)(ws + 0x40000);
    int*   rp     = cnt;
    int*   cursor = (int*)(ws + 0x80000);
    int*   bsum   = (int*)(ws + 0xB2000);
    int*   srcs   = (int*)(ws + 0xC0000);
    unsigned short* wsplit = (unsigned short*)(ws + (size_t)4 * 1024 * 1024);
    char* p = ws + (size_t)5 * 1024 * 1024;
    unsigned short* h1 = (unsigned short*)p; p += (size_t)N * H1v * sizeof(unsigned short);
    float*          a1 = (float*)p;          p += (size_t)N * H1v * sizeof(float);
    unsigned short* h2 = (unsigned short*)p; p += (size_t)N * H2v * sizeof(unsigned short);
    unsigned short* h3 = (unsigned short*)p;

    // CSR build + weight split: 5 dispatches
    k_init<<<64 + (N + 256) / 256, 256, 0, stream>>>(W1, wsplit, cnt);
    k_hist<<<(E + 255) / 256, 256, 0, stream>>>(dst, cnt);
    k_scan_part<<<NBLK, 256, 0, stream>>>(cnt, bsum);
    k_scan_final<<<NBLK, 256, 0, stream>>>(cnt, bsum, rp, cursor, dinv);
    k_permute<<<(E + 255) / 256, 256, 0, stream>>>(src, dst, cursor, srcs);

    // ---- layer 1: 512 -> 256 (MFMA, BK=64 double-buffer, 64x128 tiles), ReLU ----
    dim3 g1((N + 63) / 64, 2);
    k_gemm1_mfma<<<g1, 256, 0, stream>>>(x, wsplit, dinv, h1);
    k_agg_d256<<<(N + 3) / 4, 256, 0, stream>>>(h1, rp, srcs, dinv, b1, a1);

    // ---- layer 2: 256 -> 32, ReLU ----
    k_gemm2<<<N / 8, 256, 0, stream>>>(a1, W2, dinv, h2);

    // ---- fused: agg(h2) + GEMM3 -> h3 ----
    k_agg32_gemm3<<<N / 8, 256, 0, stream>>>(h2, rp, srcs, dinv, b2, W3, h3);

    // ---- final aggregation -> out ----
    k_agg16<<<(N + 15) / 16, 256, 0, stream>>>(h3, rp, srcs, dinv, b3, out);
}

// Round 7
// 425.891 us; speedup vs baseline: 1.8352x; 1.0248x over previous
//
#include <hip/hip_runtime.h>

// Problem constants (from reference)
constexpr int N   = 50000;
constexpr int E   = 800000;
constexpr int FIN = 512;
constexpr int H1v = 256;
constexpr int H2v = 32;
constexpr int Cv  = 16;

constexpr int NBLK = (N + 1023) / 1024;  // 49 scan blocks

typedef __attribute__((ext_vector_type(8))) short short8;            // 8 bf16 (MFMA frag)
typedef __attribute__((ext_vector_type(4))) float f32x4;             // MFMA C/D frag
typedef __attribute__((ext_vector_type(4))) unsigned short us4;      // 4 bf16
typedef __attribute__((ext_vector_type(8))) unsigned short us8;      // 8 bf16 (16 B)
typedef __attribute__((ext_vector_type(4))) unsigned int uint4v;

// fp32 -> bf16 round-to-nearest-even, and back
__device__ inline unsigned short f2bf(float f) {
    unsigned u = __float_as_uint(f);
    return (unsigned short)((u + 0x7FFFu + ((u >> 16) & 1u)) >> 16);
}
__device__ inline float bf2f(unsigned short b) { return __uint_as_float(((unsigned)b) << 16); }

// ---------------- init: cnt zeroing + W1 split, fused (independent data) --------
// Blocks 0..63: W1 split into bf16 hi/lo MFMA B-frag layout.
// Blocks 64.. : cnt[0..N] = 0.
// W-frag layout: tile (ktg 0..15, ntg 0..15): B[k][n], k=ktg*32+(l>>4)*8+j,
// n=ntg*16+(l&15); tile base = ((ktg*16+ntg)*2)*512; hi at +l*8, lo at +512+l*8.

__global__ __launch_bounds__(256) void k_init(const float* __restrict__ W,
                                              unsigned short* __restrict__ Wf,
                                              int* __restrict__ cnt) {
    const int b = blockIdx.x;
    if (b < 64) {
        int t = b * 256 + threadIdx.x;  // 0..16383
        int l = t & 63, nt = (t >> 6) & 15, kt = t >> 10;
        int n = nt * 16 + (l & 15);
        int kb = kt * 32 + (l >> 4) * 8;
        short8 h8, l8;
#pragma unroll
        for (int j = 0; j < 8; ++j) {
            float w = W[(size_t)(kb + j) * H1v + n];
            unsigned short h = f2bf(w);
            h8[j] = (short)h;
            l8[j] = (short)f2bf(w - bf2f(h));
        }
        size_t base = ((size_t)(kt * 16 + nt) * 2) * 512 + (size_t)l * 8;
        *(short8*)(Wf + base) = h8;
        *(short8*)(Wf + base + 512) = l8;
    } else {
        int i = (b - 64) * 256 + threadIdx.x;
        if (i <= N) cnt[i] = 0;
    }
}

// ---------------- degree histogram / CSR build ----------------

__global__ __launch_bounds__(256) void k_hist(const int* __restrict__ dst,
                                              int* __restrict__ cnt) {
    int e = blockIdx.x * 256 + threadIdx.x;
    if (e < E) atomicAdd(&cnt[dst[e]], 1);
}

// Phase 1: per-block (1024 elems) sums.
__global__ __launch_bounds__(256) void k_scan_part(const int* __restrict__ cnt,
                                                   int* __restrict__ bsum) {
    __shared__ int red[256];
    const int t = threadIdx.x;
    const int base = blockIdx.x * 1024 + t * 4;
    int s = 0;
#pragma unroll
    for (int i = 0; i < 4; ++i) {
        int idx = base + i;
        if (idx < N) s += cnt[idx];
    }
    red[t] = s;
    __syncthreads();
    for (int off = 128; off > 0; off >>= 1) {
        if (t < off) red[t] += red[t + off];
        __syncthreads();
    }
    if (t == 0) bsum[blockIdx.x] = red[0];
}

// Phase 2 (fused top + final): block offset computed in-block from bsum (49 ints,
// one wave), then block-local scan -> row_ptr, cursor, dinv. In-place safe vs cnt:
// each block reads only its own disjoint 1024-range into registers before writes.
__global__ __launch_bounds__(256) void k_scan_final(const int* __restrict__ cnt,
                                                    const int* __restrict__ bsum,
                                                    int* __restrict__ row_ptr,
                                                    int* __restrict__ cursor,
                                                    float* __restrict__ dinv) {
    __shared__ int sums[256];
    __shared__ int s_bofs, s_tot;
    const int t = threadIdx.x;

    if (t < 64) {  // one wave: prefix-of-my-block + grand total over bsum[49]
        int v = (t < NBLK) ? bsum[t] : 0;
        int pre = (t < (int)blockIdx.x) ? v : 0;
#pragma unroll
        for (int off = 32; off > 0; off >>= 1) {
            pre += __shfl_down(pre, off, 64);
            v   += __shfl_down(v, off, 64);
        }
        if (t == 0) { s_bofs = pre; s_tot = v; }
    }

    const int base = blockIdx.x * 1024 + t * 4;
    int v[4];
    int local = 0;
#pragma unroll
    for (int i = 0; i < 4; ++i) {
        int idx = base + i;
        v[i] = (idx < N) ? cnt[idx] : 0;
        local += v[i];
    }
    sums[t] = local;
    __syncthreads();
    for (int off = 1; off < 256; off <<= 1) {
        int u = (t >= off) ? sums[t - off] : 0;
        __syncthreads();
        sums[t] += u;
        __syncthreads();
    }
    int run = s_bofs + sums[t] - local;  // exclusive thread offset
#pragma unroll
    for (int i = 0; i < 4; ++i) {
        int idx = base + i;
        if (idx < N) {
            row_ptr[idx] = run;
            cursor[idx] = run;
            dinv[idx] = rsqrtf(1.0f + (float)v[i]);  // +1 self-loop
        }
        run += v[i];
    }
    if (blockIdx.x == NBLK - 1 && t == 0) row_ptr[N] = s_tot;  // == E
}

__global__ __launch_bounds__(256) void k_permute(const int* __restrict__ src,
                                                 const int* __restrict__ dst,
                                                 int* __restrict__ cursor,
                                                 int* __restrict__ srcs) {
    int e = blockIdx.x * 256 + threadIdx.x;
    if (e < E) {
        int pos = atomicAdd(&cursor[dst[e]], 1);
        srcs[pos] = src[e];
    }
}

// ---------------- GEMM 1 (MFMA, split-bf16 x3): [N,512]@[512,256] ---------------
// ROUND 15: gemm1 frozen at the R14 equal-best (80us, conflict-free BK=64).
// Six-round ledger: A-staging null, issue-order null, barrier-halving null,
// B-via-LDS -18%, occupancy 2->4 blk/CU +38% (the only win), 8-wave forced
// spill (V+A unified budget ~96/wave). All pipes <=25%; lockstep phase
// serialization is the residual and needs inline-asm scheduling to break (m97
// precedent). EV of further gemm1 rounds is low -> this round attacks the
// ~355us of non-gemm kernels (aggregations) instead.

__device__ inline void split_pair(float x0, float x1, unsigned& hp, unsigned& lp) {
    unsigned u0 = __float_as_uint(x0), u1 = __float_as_uint(x1);
    unsigned h0 = u0 & 0xffff0000u, h1 = u1 & 0xffff0000u;
    float l0 = x0 - __uint_as_float(h0);
    float l1 = x1 - __uint_as_float(h1);
    hp = __builtin_amdgcn_perm(u1, u0, 0x07060302u);  // [u0.hi16, u1.hi16]
    lp = __builtin_amdgcn_perm(__float_as_uint(l1), __float_as_uint(l0), 0x07060302u);
}

__device__ inline void split_frag(const float4& a, const float4& b, short8& hi, short8& lo) {
    unsigned h0, h1, h2, h3, l0, l1, l2, l3;
    split_pair(a.x, a.y, h0, l0);
    split_pair(a.z, a.w, h1, l1);
    split_pair(b.x, b.y, h2, l2);
    split_pair(b.z, b.w, h3, l3);
    uint4v h, l;
    h[0] = h0; h[1] = h1; h[2] = h2; h[3] = h3;
    l[0] = l0; l[1] = l1; l[2] = l2; l[3] = l3;
    hi = __builtin_bit_cast(short8, h);
    lo = __builtin_bit_cast(short8, l);
}

// Stage one 64-row x 64-col fp32 X tile into LDS (16 KB), XOR-swizzled.
__device__ inline void stage_x_tile(const float* __restrict__ X, int brow, int k0,
                                    float* lds, int tid) {
    const int wbase = tid & ~63;  // wave-uniform chunk base
#pragma unroll
    for (int c = 0; c < 4; ++c) {
        int q = c * 256 + tid;
        int row = q >> 4;
        int gc = ((q & 15) ^ (row & 15)) << 2;  // swizzled source col (floats)
        int r = brow + row;
        const float* src = X + (size_t)(r < N ? r : 0) * FIN + k0 + gc;
        float* dst = lds + (size_t)(c * 256 + wbase) * 4;  // wave-uniform, lane adds 16B
        __builtin_amdgcn_global_load_lds((const __attribute__((address_space(1))) void*)src,
                                         (__attribute__((address_space(3))) void*)dst,
                                         16, 0, 0);
    }
}

__global__ __launch_bounds__(256, 4) void k_gemm1_mfma(const float* __restrict__ X,
                                                       const unsigned short* __restrict__ Wf,
                                                       const float* __restrict__ dinv,
                                                       unsigned short* __restrict__ Hout) {
    __shared__ float As[2][4096];  // 2 x (64 rows x 64 cols) fp32 = 32 KB
    const int tid = threadIdx.x;
    const int w = tid >> 6, l = tid & 63;
    const int wr = w >> 1, wc = w & 1;        // wave: 32-row group x 64-col group
    const int brow = blockIdx.x * 64;         // block row base
    const int row0 = brow + wr * 32;          // this wave's global row base
    const int wrow = wr * 32;                 // this wave's LDS-local row base
    const int colb = blockIdx.y;
    const int lm = l & 15;
    const int lk2 = (l >> 4) * 2;             // fragment granule pair base (16B units)

    // B frag lane pointer (tiles ntg = colb*8 + wc*4 + j)
    const unsigned short* bp0 = Wf + (size_t)(colb * 8 + wc * 4) * 1024 + (size_t)l * 8;

    f32x4 acc[2][4];
#pragma unroll
    for (int i = 0; i < 2; ++i)
#pragma unroll
        for (int j = 0; j < 4; ++j) acc[i][j] = (f32x4)0.f;

    // prologue: stage K-tile 0 (64 cols)
    stage_x_tile(X, brow, 0, As[0], tid);

    for (int kt = 0; kt < 8; ++kt) {
        const int cur = kt & 1;
        __syncthreads();  // drains vmcnt(0): As[cur] staged & visible

        // B frags for sub-step 0 (ktg = 2*kt), L2-hot frag layout
        const unsigned short* bpA = bp0 + (size_t)(2 * kt) * 16384;
        short8 B0h[4], B0l[4];
#pragma unroll
        for (int j = 0; j < 4; ++j) {
            B0h[j] = *(const short8*)(bpA + j * 1024);
            B0l[j] = *(const short8*)(bpA + j * 1024 + 512);
        }

        // stage next 64-col K-tile (completes during the two MFMA phases)
        if (kt < 7) stage_x_tile(X, brow, (kt + 1) * 64, As[cur ^ 1], tid);

        const float* Ab = As[cur];

        // ---- sub-step 0: granules [0,8) ----
        short8 Ah[2], Al[2];
#pragma unroll
        for (int i = 0; i < 2; ++i) {
            int row = wrow + i * 16 + lm;
            const float* rbp = Ab + row * 64;
            int p = row & 15;
            float4 a0 = *(const float4*)(rbp + ((lk2 ^ p) << 2));
            float4 a1 = *(const float4*)(rbp + (((lk2 + 1) ^ p) << 2));
            split_frag(a0, a1, Ah[i], Al[i]);
        }

        // B frags for sub-step 1 issued BEFORE MFMA block 0 (latency covered by it)
        const unsigned short* bpB = bpA + 16384;
        short8 B1h[4], B1l[4];
#pragma unroll
        for (int j = 0; j < 4; ++j) {
            B1h[j] = *(const short8*)(bpB + j * 1024);
            B1l[j] = *(const short8*)(bpB + j * 1024 + 512);
        }

#pragma unroll
        for (int i = 0; i < 2; ++i)
#pragma unroll
            for (int j = 0; j < 4; ++j) {
                acc[i][j] = __builtin_amdgcn_mfma_f32_16x16x32_bf16(Ah[i], B0h[j], acc[i][j], 0, 0, 0);
                acc[i][j] = __builtin_amdgcn_mfma_f32_16x16x32_bf16(Ah[i], B0l[j], acc[i][j], 0, 0, 0);
                acc[i][j] = __builtin_amdgcn_mfma_f32_16x16x32_bf16(Al[i], B0h[j], acc[i][j], 0, 0, 0);
            }

        // ---- sub-step 1: granules [8,16) ----
#pragma unroll
        for (int i = 0; i < 2; ++i) {
            int row = wrow + i * 16 + lm;
            const float* rbp = Ab + row * 64;
            int p = row & 15;
            int g0 = lk2 + 8;
            float4 a0 = *(const float4*)(rbp + ((g0 ^ p) << 2));
            float4 a1 = *(const float4*)(rbp + (((g0 + 1) ^ p) << 2));
            split_frag(a0, a1, Ah[i], Al[i]);
        }

#pragma unroll
        for (int i = 0; i < 2; ++i)
#pragma unroll
            for (int j = 0; j < 4; ++j) {
                acc[i][j] = __builtin_amdgcn_mfma_f32_16x16x32_bf16(Ah[i], B1h[j], acc[i][j], 0, 0, 0);
                acc[i][j] = __builtin_amdgcn_mfma_f32_16x16x32_bf16(Ah[i], B1l[j], acc[i][j], 0, 0, 0);
                acc[i][j] = __builtin_amdgcn_mfma_f32_16x16x32_bf16(Al[i], B1h[j], acc[i][j], 0, 0, 0);
            }
    }

    // ---- epilogue: C row = (l>>4)*4 + reg, col = l&15 ; *dinv[row], store bf16 ----
    const int col0 = colb * 128 + wc * 64;
#pragma unroll
    for (int i = 0; i < 2; ++i) {
        int rbase = row0 + i * 16 + (l >> 4) * 4;
        float dv[4];
        bool okr[4];
#pragma unroll
        for (int r = 0; r < 4; ++r) {
            int rr = rbase + r;
            okr[r] = rr < N;
            dv[r] = okr[r] ? dinv[rr] : 0.f;
        }
#pragma unroll
        for (int j = 0; j < 4; ++j) {
            int col = col0 + j * 16 + lm;
#pragma unroll
            for (int r = 0; r < 4; ++r)
                if (okr[r]) Hout[(size_t)(rbase + r) * H1v + col] = f2bf(acc[i][j][r] * dv[r]);
        }
    }
}

// ---------------- GEMM 2: [N,256] @ [256,32] fp32 in, *dinv, bf16 out ----------------

__global__ __launch_bounds__(256) void k_gemm2(const float* __restrict__ A,
                                               const float* __restrict__ W,
                                               const float* __restrict__ dinv,
                                               unsigned short* __restrict__ Hout) {
    __shared__ float Ws[H1v * H2v];  // 32 KB
    const int tid = threadIdx.x;
#pragma unroll
    for (int i = 0; i < 8; ++i) {
        int off = tid * 4 + i * 1024;
        *(float4*)(&Ws[off]) = *(const float4*)(W + off);
    }
    __syncthreads();

    const int row = blockIdx.x * 8 + (tid >> 5);
    const int col = tid & 31;
    if (row >= N) return;
    const float* arow = A + (size_t)row * H1v;
    float sum = 0.f;
#pragma unroll 4
    for (int k = 0; k < H1v; k += 4) {
        float4 a4 = *(const float4*)(arow + k);
        sum = fmaf(a4.x, Ws[(k + 0) * H2v + col], sum);
        sum = fmaf(a4.y, Ws[(k + 1) * H2v + col], sum);
        sum = fmaf(a4.z, Ws[(k + 2) * H2v + col], sum);
        sum = fmaf(a4.w, Ws[(k + 3) * H2v + col], sum);
    }
    Hout[(size_t)row * H2v + col] = f2bf(sum * dinv[row]);
}

// ---------------- CSR aggregation D=256 (atomic-free, bf16 msgs, fp32 accum) -----
// ROUND 15: 2 dst rows per WAVE (32-lane halves), us8 16B gathers (one
// wave-instr per edge-pair vs one per edge), 4-deep unroll -> 8 outstanding
// 16B loads/wave. Same per-dim summation order (bit-identical output).

__global__ __launch_bounds__(256) void k_agg_d256(const unsigned short* __restrict__ h,
                                                  const int* __restrict__ rp,
                                                  const int* __restrict__ srcs,
                                                  const float* __restrict__ dinv,
                                                  const float* __restrict__ bias,
                                                  float* __restrict__ out) {
    const int half = threadIdx.x >> 5;     // row slot 0..7 in block
    const int lane = threadIdx.x & 31;
    const int d = blockIdx.x * 8 + half;
    if (d >= N) return;
    const int beg = rp[d], end = rp[d + 1];
    const int fo = lane * 8;               // 8 bf16 = 16 B per lane
    const unsigned short* hb = h + fo;
    us8 sv = *(const us8*)(hb + (size_t)d * H1v);  // self-loop
    float a[8];
#pragma unroll
    for (int q = 0; q < 8; ++q) a[q] = bf2f(sv[q]);
    int j = beg;
    for (; j + 3 < end; j += 4) {  // 4 independent 16B gathers per row
        int s0 = srcs[j], s1 = srcs[j + 1], s2 = srcs[j + 2], s3 = srcs[j + 3];
        us8 v0 = *(const us8*)(hb + (size_t)s0 * H1v);
        us8 v1 = *(const us8*)(hb + (size_t)s1 * H1v);
        us8 v2 = *(const us8*)(hb + (size_t)s2 * H1v);
        us8 v3 = *(const us8*)(hb + (size_t)s3 * H1v);
#pragma unroll
        for (int q = 0; q < 8; ++q)
            a[q] += bf2f(v0[q]) + bf2f(v1[q]) + bf2f(v2[q]) + bf2f(v3[q]);
    }
    for (; j < end; ++j) {
        us8 v = *(const us8*)(hb + (size_t)srcs[j] * H1v);
#pragma unroll
        for (int q = 0; q < 8; ++q) a[q] += bf2f(v[q]);
    }
    const float di = dinv[d];
    const float4 b0 = *(const float4*)(bias + fo);
    const float4 b1 = *(const float4*)(bias + fo + 4);
    float4 o0, o1;
    o0.x = fmaxf(fmaf(di, a[0], b0.x), 0.f);
    o0.y = fmaxf(fmaf(di, a[1], b0.y), 0.f);
    o0.z = fmaxf(fmaf(di, a[2], b0.z), 0.f);
    o0.w = fmaxf(fmaf(di, a[3], b0.w), 0.f);
    o1.x = fmaxf(fmaf(di, a[4], b1.x), 0.f);
    o1.y = fmaxf(fmaf(di, a[5], b1.y), 0.f);
    o1.z = fmaxf(fmaf(di, a[6], b1.z), 0.f);
    o1.w = fmaxf(fmaf(di, a[7], b1.w), 0.f);
    *(float4*)(out + (size_t)d * H1v + fo) = o0;
    *(float4*)(out + (size_t)d * H1v + fo + 4) = o1;
}

// ---------------- fused: agg over h2 (D=32) + GEMM3 [32x16] -> h3 bf16 ----------
// ROUND 15: 16 rows/block (was 8). Phase 1: thread (sub, fg) handles 2 dims via
// 4B paired loads (16 lanes x 4B = full 64B line per edge-row); 4 rows/wave ->
// 16 outstanding gathers with unroll 4. Phase 2: 16x16 = all 256 threads active.

__global__ __launch_bounds__(256) void k_agg32_gemm3(const unsigned short* __restrict__ h2,
                                                     const int* __restrict__ rp,
                                                     const int* __restrict__ srcs,
                                                     const float* __restrict__ dinv,
                                                     const float* __restrict__ b2,
                                                     const float* __restrict__ W3,
                                                     unsigned short* __restrict__ h3) {
    __shared__ float als[16][33];      // +1 pad
    __shared__ float W3s[H2v * Cv];    // 512 floats
    const int t = threadIdx.x;
    *(float2*)(&W3s[t * 2]) = *(const float2*)(W3 + t * 2);

    const int sub = t >> 4, fg = t & 15;   // row slot, dim-pair group
    const int d = blockIdx.x * 16 + sub;   // N % 16 == 0
    const int beg = rp[d], end = rp[d + 1];
    const unsigned short* h2b = h2 + fg * 2;
    unsigned sv = *(const unsigned*)(h2b + (size_t)d * H2v);
    float a0 = __uint_as_float(sv << 16);              // dim fg*2
    float a1 = __uint_as_float(sv & 0xffff0000u);      // dim fg*2+1
    int j = beg;
    for (; j + 3 < end; j += 4) {
        unsigned v0 = *(const unsigned*)(h2b + (size_t)srcs[j] * H2v);
        unsigned v1 = *(const unsigned*)(h2b + (size_t)srcs[j + 1] * H2v);
        unsigned v2 = *(const unsigned*)(h2b + (size_t)srcs[j + 2] * H2v);
        unsigned v3 = *(const unsigned*)(h2b + (size_t)srcs[j + 3] * H2v);
        a0 += __uint_as_float(v0 << 16) + __uint_as_float(v1 << 16)
            + __uint_as_float(v2 << 16) + __uint_as_float(v3 << 16);
        a1 += __uint_as_float(v0 & 0xffff0000u) + __uint_as_float(v1 & 0xffff0000u)
            + __uint_as_float(v2 & 0xffff0000u) + __uint_as_float(v3 & 0xffff0000u);
    }
    for (; j < end; ++j) {
        unsigned v = *(const unsigned*)(h2b + (size_t)srcs[j] * H2v);
        a0 += __uint_as_float(v << 16);
        a1 += __uint_as_float(v & 0xffff0000u);
    }
    const float di = dinv[d];
    als[sub][fg * 2]     = fmaxf(fmaf(di, a0, b2[fg * 2]), 0.f);
    als[sub][fg * 2 + 1] = fmaxf(fmaf(di, a1, b2[fg * 2 + 1]), 0.f);
    __syncthreads();

    const int row = t >> 4, col = t & 15;
    float sum = 0.f;
#pragma unroll
    for (int k = 0; k < H2v; ++k) sum = fmaf(als[row][k], W3s[k * Cv + col], sum);
    const int gr = blockIdx.x * 16 + row;
    h3[(size_t)gr * Cv + col] = f2bf(sum * dinv[gr]);
}

// ---------------- final aggregation over h3 (D=16) -> out fp32 ----------------
// ROUND 15: 32 rows/block, 4B paired-dim gathers (8 lanes x 4B = 32B row), 8
// rows/wave in flight, float2 stores.

__global__ __launch_bounds__(256) void k_agg16(const unsigned short* __restrict__ h,
                                               const int* __restrict__ rp,
                                               const int* __restrict__ srcs,
                                               const float* __restrict__ dinv,
                                               const float* __restrict__ bias,
                                               float* __restrict__ out) {
    const int sub = threadIdx.x >> 3;      // row slot 0..31
    const int fg = threadIdx.x & 7;        // dim-pair group
    const int d = blockIdx.x * 32 + sub;
    if (d >= N) return;
    const int beg = rp[d], end = rp[d + 1];
    const unsigned short* hb = h + fg * 2;
    unsigned sv = *(const unsigned*)(hb + (size_t)d * Cv);
    float a0 = __uint_as_float(sv << 16);
    float a1 = __uint_as_float(sv & 0xffff0000u);
    int j = beg;
    for (; j + 3 < end; j += 4) {
        unsigned v0 = *(const unsigned*)(hb + (size_t)srcs[j] * Cv);
        unsigned v1 = *(const unsigned*)(hb + (size_t)srcs[j + 1] * Cv);
        unsigned v2 = *(const unsigned*)(hb + (size_t)srcs[j + 2] * Cv);
        unsigned v3 = *(const unsigned*)(hb + (size_t)srcs[j + 3] * Cv);
        a0 += __uint_as_float(v0 << 16) + __uint_as_float(v1 << 16)
            + __uint_as_float(v2 << 16) + __uint_as_float(v3 << 16);
        a1 += __uint_as_float(v0 & 0xffff0000u) + __uint_as_float(v1 & 0xffff0000u)
            + __uint_as_float(v2 & 0xffff0000u) + __uint_as_float(v3 & 0xffff0000u);
    }
    for (; j < end; ++j) {
        unsigned v = *(const unsigned*)(hb + (size_t)srcs[j] * Cv);
        a0 += __uint_as_float(v << 16);
        a1 += __uint_as_float(v & 0xffff0000u);
    }
    const float di = dinv[d];
    float2 o;
    o.x = fmaf(di, a0, bias[fg * 2]);
    o.y = fmaf(di, a1, bias[fg * 2 + 1]);
    *(float2*)(out + (size_t)d * Cv + fg * 2) = o;
}

// ---------------- launch ----------------

extern "C" void kernel_launch(void* const* d_in, const int* in_sizes, int n_in,
                              void* d_out, int out_size, void* d_ws, size_t ws_size,
                              hipStream_t stream) {
    const float* x  = (const float*)d_in[0];
    const int*   ei = (const int*)d_in[1];
    const float* W1 = (const float*)d_in[2];
    const float* b1 = (const float*)d_in[3];
    const float* W2 = (const float*)d_in[4];
    const float* b2 = (const float*)d_in[5];
    const float* W3 = (const float*)d_in[6];
    const float* b3 = (const float*)d_in[7];
    const int* src = ei;       // edge_index[0]
    const int* dst = ei + E;   // edge_index[1]
    float* out = (float*)d_out;

    // Workspace layout (bytes):
    // [0       ] dinv    float[50000]
    // [0x40000 ] cnt/rp  int[50001]   (in-place scan)
    // [0x80000 ] cursor  int[50000]
    // [0xB2000 ] bsum    int[49]
    // [0xC0000 ] srcs    int[800000]
    // [4 MiB   ] Wsplit  ushort[262144]  (512 KB)
    // [5 MiB   ] h1 bf16, a1 fp32, h2 bf16, h3 bf16   (a2 eliminated)
    char* ws = (char*)d_ws;
    float* dinv   = (float*)ws;
    int*   cnt    = (int*)(ws + 0x40000);
    int*   rp     = cnt;
    int*   cursor = (int*)(ws + 0x80000);
    int*   bsum   = (int*)(ws + 0xB2000);
    int*   srcs   = (int*)(ws + 0xC0000);
    unsigned short* wsplit = (unsigned short*)(ws + (size_t)4 * 1024 * 1024);
    char* p = ws + (size_t)5 * 1024 * 1024;
    unsigned short* h1 = (unsigned short*)p; p += (size_t)N * H1v * sizeof(unsigned short);
    float*          a1 = (float*)p;          p += (size_t)N * H1v * sizeof(float);
    unsigned short* h2 = (unsigned short*)p; p += (size_t)N * H2v * sizeof(unsigned short);
    unsigned short* h3 = (unsigned short*)p;

    // CSR build + weight split: 5 dispatches
    k_init<<<64 + (N + 256) / 256, 256, 0, stream>>>(W1, wsplit, cnt);
    k_hist<<<(E + 255) / 256, 256, 0, stream>>>(dst, cnt);
    k_scan_part<<<NBLK, 256, 0, stream>>>(cnt, bsum);
    k_scan_final<<<NBLK, 256, 0, stream>>>(cnt, bsum, rp, cursor, dinv);
    k_permute<<<(E + 255) / 256, 256, 0, stream>>>(src, dst, cursor, srcs);

    // ---- layer 1: 512 -> 256 (MFMA, BK=64 double-buffer, 64x128 tiles), ReLU ----
    dim3 g1((N + 63) / 64, 2);
    k_gemm1_mfma<<<g1, 256, 0, stream>>>(x, wsplit, dinv, h1);
    k_agg_d256<<<(N + 7) / 8, 256, 0, stream>>>(h1, rp, srcs, dinv, b1, a1);

    // ---- layer 2: 256 -> 32, ReLU ----
    k_gemm2<<<N / 8, 256, 0, stream>>>(a1, W2, dinv, h2);

    // ---- fused: agg(h2) + GEMM3 -> h3 ----
    k_agg32_gemm3<<<N / 16, 256, 0, stream>>>(h2, rp, srcs, dinv, b2, W3, h3);

    // ---- final aggregation -> out ----
    k_agg16<<<(N + 31) / 32, 256, 0, stream>>>(h3, rp, srcs, dinv, b3, out);
}